// Round 5
// baseline (505.180 us; speedup 1.0000x reference)
//
#include <hip/hip_runtime.h>
#include <stdint.h>

// BondFastAttention on MI355X (gfx950)
// B=64 graphs x L=1024 bonds, HID=512, HEADS=8, D=64. Contiguous equal scopes
// -> pad_sequence == reshape, so batch_scopes is ignored.
//
// Pipeline (round 5):
//   K0  cvt_x:   X f32 -> bf16 (Xb)
//   K0b cvt_w:   Wq|Wk|Wv -> Wqkv bf16 (1536x512), Wo -> bf16
//   K1  gemm_qkv: QKV = Xb @ Wqkv^T -- PERSISTENT: grid=256 (1 block/CU),
//                block tm owns a 256-row M-panel, streams 6 N-tiles x 8
//                K-tiles as 48 uniform steps; 2-deep LDS ring + counted
//                vmcnt(8) ledger rolls across tile boundaries (1 prologue).
//   R1  reduce_gq: gq partials per (b,h,Lchunk)
//   R2  reduce_gk: gk partials (folds gq partials)
//   R3  att_k:   att = relu([V|Q] @ [M|I]^T), M = Wr*gk (identity-MFMA Q-add)
//   K3  gemm_ln: out = LN(att @ Wo^T + bo)*g + b
//
// ws: Xb 0..67108864 | Wqkv ..68681728 | Wob ..69206016 | QKV ..270532608 |
//     gq_part ..271056896 | gk_part ..271581184
// att aliases Xb (Xb dead after K1).

#define SCALE_F 0.125f   // D^-0.5
#define EPSF 1e-5f

typedef __attribute__((ext_vector_type(8))) short short8;
typedef __attribute__((ext_vector_type(4))) float float4v;
typedef unsigned short ushort_t;

__device__ __forceinline__ ushort_t f2bf(float f) {
  uint32_t u = __builtin_bit_cast(uint32_t, f);
  u += 0x7fffu + ((u >> 16) & 1u);          // round-to-nearest-even
  return (ushort_t)(u >> 16);
}
__device__ __forceinline__ float bf2f(ushort_t s) {
  uint32_t u = ((uint32_t)s) << 16;
  return __builtin_bit_cast(float, u);
}

// async global->LDS, 16B per lane; LDS dest = wave-uniform base + lane*16
__device__ __forceinline__ void gload16(const void* g, void* l) {
  __builtin_amdgcn_global_load_lds(
      (__attribute__((address_space(1))) char*)(char*)const_cast<void*>(g),
      (__attribute__((address_space(3))) char*)(char*)l, 16, 0, 0);
}

#define SBAR() __builtin_amdgcn_s_barrier()
#define LGKM0() do { __builtin_amdgcn_sched_barrier(0);                 \
                     asm volatile("s_waitcnt lgkmcnt(0)" ::: "memory"); \
                     __builtin_amdgcn_sched_barrier(0); } while (0)

// ---------------- K0: X f32 -> bf16 (8 elems/thread) ----------------
__global__ __launch_bounds__(256) void cvt_x(const float* __restrict__ X,
                                             ushort_t* __restrict__ Xb) {
  const int i = blockIdx.x * 256 + threadIdx.x;
  const float4v* src = (const float4v*)X;
  float4v v0 = src[(size_t)i * 2];
  float4v v1 = src[(size_t)i * 2 + 1];
  short8 o;
#pragma unroll
  for (int j = 0; j < 4; ++j) {
    o[j]     = (short)f2bf(v0[j]);
    o[j + 4] = (short)f2bf(v1[j]);
  }
  ((short8*)Xb)[i] = o;
}

// ---------------- K0b: weights -> bf16 ----------------
__global__ __launch_bounds__(256) void cvt_w(const float* __restrict__ Wq,
                                             const float* __restrict__ Wk,
                                             const float* __restrict__ Wv,
                                             const float* __restrict__ Wo,
                                             ushort_t* __restrict__ Wqkv,
                                             ushort_t* __restrict__ Wob) {
  const int i = blockIdx.x * 256 + threadIdx.x;   // 1,048,576 total
  if (i < 262144)        Wqkv[i] = f2bf(Wq[i]);
  else if (i < 524288)   Wqkv[i] = f2bf(Wk[i - 262144]);
  else if (i < 786432)   Wqkv[i] = f2bf(Wv[i - 524288]);
  else                   Wob[i - 786432] = f2bf(Wo[i - 786432]);
}

// ---------------- K1: persistent QKV GEMM ----------------
// grid 256, 512 thr = 8 waves (2 wr x 4 wc), wave tile 128x64. Step s in
// [0,48): tn = s>>3, kt = s&7. LDS ring: slot s&1 holds K-tile s (A 32 KB +
// B 32 KB), XOR-swizzled (elem (r,c2) at byte r*128 + (c2 ^ ((r&7)<<4)));
// global source pre-swizzled since global_load_lds writes linearly.
// Ledger: 8 loads/step (B(s+2) 4 + A(s+2) 4); boundary vmcnt(8) => K(s+1)
// landed. Overwrite safety: slot readers drain at an lgkmcnt(0) BEFORE the
// barrier that releases that slot's re-stage (B at BARR_a, A at BARR_b).
// Tile epilogues' stores fold into vmcnt (waits become conservative only).
__global__ __launch_bounds__(512, 2) void gemm_qkv(const ushort_t* __restrict__ A,
                                                   const ushort_t* __restrict__ Bm,
                                                   ushort_t* __restrict__ C) {
  __shared__ __align__(16) char ldsA[65536];   // 2 slots x 32 KB
  __shared__ __align__(16) char ldsB[65536];
  const int tm = blockIdx.x;                   // 256 M-panels, 1 per CU
  const int row0 = tm * 256;
  const int tid = threadIdx.x, wid = tid >> 6, lane = tid & 63;
  const int wr = wid >> 2, wc = wid & 3;
  const int lr = lane & 15, lk = lane >> 4;
  const int xr = (lr & 7) << 4;                // read-side XOR (bytes)

  auto stageA = [&](int s) {                   // A K-tile s -> slot s&1
    const int kt = s & 7;
#pragma unroll
    for (int i = 0; i < 4; ++i) {
      const int o = i * 8192 + wid * 1024 + lane * 16;
      const int r = o >> 7, x = o & 127;
      gload16((const char*)A + (size_t)(row0 + r) * 1024 + kt * 128 + (x ^ ((r & 7) << 4)),
              ldsA + (s & 1) * 32768 + i * 8192 + wid * 1024);
    }
  };
  auto stageB = [&](int s) {                   // B K-tile s -> slot s&1
    const int kt = s & 7, colb = (s >> 3) * 256;
#pragma unroll
    for (int i = 0; i < 4; ++i) {
      const int o = i * 8192 + wid * 1024 + lane * 16;
      const int r = o >> 7, x = o & 127;
      gload16((const char*)Bm + (size_t)(colb + r) * 1024 + kt * 128 + (x ^ ((r & 7) << 4)),
              ldsB + (s & 1) * 32768 + i * 8192 + wid * 1024);
    }
  };
  auto rdA = [&](int sl, int mi, int kk) -> short8 {
    return *(const short8*)(ldsA + sl * 32768 + (wr * 128 + mi * 16 + lr) * 128 +
                            ((kk * 64 + lk * 16) ^ xr));
  };
  auto rdB = [&](int sl, int ni, int kk) -> short8 {
    return *(const short8*)(ldsB + sl * 32768 + (wc * 64 + ni * 16 + lr) * 128 +
                            ((kk * 64 + lk * 16) ^ xr));
  };

  float4v acc[8][4] = {};

  // prologue: K0 (8 loads) then K1 (8); vmcnt(8) -> K0 landed
  stageA(0); stageB(0);
  stageA(1); stageB(1);
  asm volatile("s_waitcnt vmcnt(8)" ::: "memory");
  SBAR();

#pragma unroll 2
  for (int s = 0; s < 48; ++s) {
    const int sl = s & 1;
    short8 a0[4][2], a1[4][2], b[4][2];
    // ph1 reads: a0 (mi 0..3) + all b, from slot sl
#pragma unroll
    for (int mi = 0; mi < 4; ++mi)
#pragma unroll
      for (int kk = 0; kk < 2; ++kk) a0[mi][kk] = rdA(sl, mi, kk);
#pragma unroll
    for (int ni = 0; ni < 4; ++ni)
#pragma unroll
      for (int kk = 0; kk < 2; ++kk) b[ni][kk] = rdB(sl, ni, kk);
    LGKM0();                    // all A/B-slot ph1 reads in regs
    SBAR();                     // BARR_a: B slot sl free for re-stage
    if (s + 2 < 48) stageB(s + 2);
    // ph2 reads issued early (overlap MFMA1); A slot not re-staged till BARR_b
#pragma unroll
    for (int mi = 0; mi < 4; ++mi)
#pragma unroll
      for (int kk = 0; kk < 2; ++kk) a1[mi][kk] = rdA(sl, mi + 4, kk);
    __builtin_amdgcn_s_setprio(1);
#pragma unroll
    for (int kk = 0; kk < 2; ++kk)
#pragma unroll
      for (int mi = 0; mi < 4; ++mi)
#pragma unroll
        for (int ni = 0; ni < 4; ++ni)
          acc[mi][ni] = __builtin_amdgcn_mfma_f32_16x16x32_bf16(a0[mi][kk], b[ni][kk], acc[mi][ni], 0, 0, 0);
    __builtin_amdgcn_s_setprio(0);
    LGKM0();                    // a1 reads done
    SBAR();                     // BARR_b: A slot sl free for re-stage
    if (s + 2 < 48) stageA(s + 2);
    __builtin_amdgcn_s_setprio(1);
#pragma unroll
    for (int kk = 0; kk < 2; ++kk)
#pragma unroll
      for (int mi = 0; mi < 4; ++mi)
#pragma unroll
        for (int ni = 0; ni < 4; ++ni)
          acc[mi + 4][ni] = __builtin_amdgcn_mfma_f32_16x16x32_bf16(a1[mi][kk], b[ni][kk], acc[mi + 4][ni], 0, 0, 0);
    __builtin_amdgcn_s_setprio(0);
    __builtin_amdgcn_sched_barrier(0);
    if (s < 46) {
      asm volatile("s_waitcnt vmcnt(8)" ::: "memory");   // K(s+1) landed
    } else if (s == 46) {
      asm volatile("s_waitcnt vmcnt(0)" ::: "memory");   // K47 landed
    }
    SBAR();                     // BARR_c: all waves past their vmcnt
    if ((s & 7) == 7) {
      // tile epilogue: C/D col=lane&15, row=(lane>>4)*4+r (m89-verified)
      const int col0 = (s >> 3) * 256;
#pragma unroll
      for (int mi = 0; mi < 8; ++mi)
#pragma unroll
        for (int ni = 0; ni < 4; ++ni) {
          const int col = col0 + wc * 64 + ni * 16 + lr;
#pragma unroll
          for (int r = 0; r < 4; ++r) {
            const int row = row0 + wr * 128 + mi * 16 + lk * 4 + r;
            C[(size_t)row * 1536 + col] = f2bf(acc[mi][ni][r]);
            acc[mi][ni][r] = 0.0f;
          }
        }
    }
  }
}

// ---------------- R1: gq partials ----------------
// Grid 2048 = (bh=512) x (ch=4); 256 thr. Each block: 256 tokens.
__global__ __launch_bounds__(256) void reduce_gq(const ushort_t* __restrict__ QKV,
                                                 const float* __restrict__ w_alpha,
                                                 float* __restrict__ gq_part) {
  const int bx = blockIdx.x, bh = bx >> 2, ch = bx & 3;
  const int b = bh >> 3, h = bh & 7;
  const int tid = threadIdx.x, wid = tid >> 6, lane = tid & 63;
  const int rsub = lane >> 3, dch = lane & 7;
  __shared__ float red[4][64];
  float wa[8];
#pragma unroll
  for (int j = 0; j < 8; ++j) wa[j] = w_alpha[dch * 8 + j] * SCALE_F;
  const size_t base = (size_t)b * 1024 + ch * 256;
  float acc[8] = {0, 0, 0, 0, 0, 0, 0, 0};
  for (int it = 0; it < 8; ++it) {
    const size_t t = base + it * 32 + wid * 8 + rsub;
    short8 raw = *(const short8*)(QKV + t * 1536 + h * 64 + dch * 8);
    float q[8], s[8];
#pragma unroll
    for (int j = 0; j < 8; ++j) { q[j] = bf2f((ushort_t)raw[j]); s[j] = q[j] * wa[j]; }
    float m = s[0];
#pragma unroll
    for (int j = 1; j < 8; ++j) m = fmaxf(m, s[j]);
    m = fmaxf(m, __shfl_xor(m, 1)); m = fmaxf(m, __shfl_xor(m, 2)); m = fmaxf(m, __shfl_xor(m, 4));
    float e[8], sum = 0.f;
#pragma unroll
    for (int j = 0; j < 8; ++j) { e[j] = __expf(s[j] - m); sum += e[j]; }
    sum += __shfl_xor(sum, 1); sum += __shfl_xor(sum, 2); sum += __shfl_xor(sum, 4);
    const float inv = 1.0f / sum;
#pragma unroll
    for (int j = 0; j < 8; ++j) acc[j] += e[j] * inv * q[j];
  }
#pragma unroll
  for (int msk = 8; msk < 64; msk <<= 1)
#pragma unroll
    for (int j = 0; j < 8; ++j) acc[j] += __shfl_xor(acc[j], msk);
  if (lane < 8) {
#pragma unroll
    for (int j = 0; j < 8; ++j) red[wid][lane * 8 + j] = acc[j];
  }
  __syncthreads();
  if (tid < 64)
    gq_part[(size_t)bx * 64 + tid] = red[0][tid] + red[1][tid] + red[2][tid] + red[3][tid];
}

// ---------------- R2: gk partials (folds gq partials in prologue) ----------
__global__ __launch_bounds__(256) void reduce_gk(const ushort_t* __restrict__ QKV,
                                                 const float* __restrict__ w_beta,
                                                 const float* __restrict__ gq_part,
                                                 float* __restrict__ gk_part) {
  const int bx = blockIdx.x, bh = bx >> 2, ch = bx & 3;
  const int b = bh >> 3, h = bh & 7;
  const int tid = threadIdx.x, wid = tid >> 6, lane = tid & 63;
  const int rsub = lane >> 3, dch = lane & 7;
  __shared__ float red[4][64];
  __shared__ float gq_s[64];
  if (tid < 64) {
    float s = 0.f;
#pragma unroll
    for (int c = 0; c < 4; ++c) s += gq_part[(size_t)(bh * 4 + c) * 64 + tid];
    gq_s[tid] = s;
  }
  __syncthreads();
  float wb[8], gq[8];
#pragma unroll
  for (int j = 0; j < 8; ++j) {
    wb[j] = w_beta[dch * 8 + j] * SCALE_F;
    gq[j] = gq_s[dch * 8 + j];
  }
  const size_t base = (size_t)b * 1024 + ch * 256;
  float acc[8] = {0, 0, 0, 0, 0, 0, 0, 0};
  for (int it = 0; it < 8; ++it) {
    const size_t t = base + it * 32 + wid * 8 + rsub;
    short8 raw = *(const short8*)(QKV + t * 1536 + 512 + h * 64 + dch * 8);
    float p[8], s[8];
#pragma unroll
    for (int j = 0; j < 8; ++j) { p[j] = gq[j] * bf2f((ushort_t)raw[j]); s[j] = p[j] * wb[j]; }
    float m = s[0];
#pragma unroll
    for (int j = 1; j < 8; ++j) m = fmaxf(m, s[j]);
    m = fmaxf(m, __shfl_xor(m, 1)); m = fmaxf(m, __shfl_xor(m, 2)); m = fmaxf(m, __shfl_xor(m, 4));
    float e[8], sum = 0.f;
#pragma unroll
    for (int j = 0; j < 8; ++j) { e[j] = __expf(s[j] - m); sum += e[j]; }
    sum += __shfl_xor(sum, 1); sum += __shfl_xor(sum, 2); sum += __shfl_xor(sum, 4);
    const float inv = 1.0f / sum;
#pragma unroll
    for (int j = 0; j < 8; ++j) acc[j] += e[j] * inv * p[j];
  }
#pragma unroll
  for (int msk = 8; msk < 64; msk <<= 1)
#pragma unroll
    for (int j = 0; j < 8; ++j) acc[j] += __shfl_xor(acc[j], msk);
  if (lane < 8) {
#pragma unroll
    for (int j = 0; j < 8; ++j) red[wid][lane * 8 + j] = acc[j];
  }
  __syncthreads();
  if (tid < 64)
    gk_part[(size_t)bx * 64 + tid] = red[0][tid] + red[1][tid] + red[2][tid] + red[3][tid];
}

// ---------------- R3: att = relu([V|Q] @ [M|I]^T), M = Wr*gk ----------------
__global__ __launch_bounds__(256) void att_k(const ushort_t* __restrict__ QKV,
                                             const float* __restrict__ Wr,
                                             const float* __restrict__ gk_part,
                                             ushort_t* __restrict__ att) {
  const int bx = blockIdx.x, bh = bx >> 2, tc = bx & 3;
  const int b = bh >> 3, h = bh & 7;
  const int tid = threadIdx.x, wid = tid >> 6, lane = tid & 63;
  __shared__ float gk_s[64];
  __shared__ __align__(16) ushort_t Ml[64 * 72];
  if (tid < 64) {
    float s = 0.f;
#pragma unroll
    for (int c = 0; c < 4; ++c) s += gk_part[(size_t)(bh * 4 + c) * 64 + tid];
    gk_s[tid] = s;
  }
  __syncthreads();
  for (int i = tid; i < 4096; i += 256) {
    const int e = i >> 6, d = i & 63;
    Ml[e * 72 + d] = f2bf(Wr[i] * gk_s[d]);
  }
  __syncthreads();
  const int lr = lane & 15, lk = lane >> 4;
  short8 bfr[4][2], bfi[4][2];
#pragma unroll
  for (int ni = 0; ni < 4; ++ni)
#pragma unroll
    for (int ks = 0; ks < 2; ++ks) {
      bfr[ni][ks] = *(const short8*)&Ml[(ni * 16 + lr) * 72 + ks * 32 + lk * 8];
#pragma unroll
      for (int j = 0; j < 8; ++j)
        bfi[ni][ks][j] = (ni * 16 + lr == ks * 32 + lk * 8 + j) ? (short)0x3F80 : (short)0;
    }
  const size_t tw = (size_t)b * 1024 + tc * 256 + wid * 64;
  float4v oacc[4][4] = {};
#pragma unroll
  for (int ks = 0; ks < 2; ++ks) {
    short8 a[4], aq[4];
#pragma unroll
    for (int mi = 0; mi < 4; ++mi) {
      const size_t t = tw + mi * 16 + lr;
      a[mi]  = *(const short8*)(QKV + t * 1536 + 1024 + h * 64 + ks * 32 + lk * 8);  // V
      aq[mi] = *(const short8*)(QKV + t * 1536 +        h * 64 + ks * 32 + lk * 8);  // Q
    }
#pragma unroll
    for (int mi = 0; mi < 4; ++mi)
#pragma unroll
      for (int ni = 0; ni < 4; ++ni) {
        oacc[mi][ni] = __builtin_amdgcn_mfma_f32_16x16x32_bf16(a[mi],  bfr[ni][ks], oacc[mi][ni], 0, 0, 0);
        oacc[mi][ni] = __builtin_amdgcn_mfma_f32_16x16x32_bf16(aq[mi], bfi[ni][ks], oacc[mi][ni], 0, 0, 0);
      }
  }
#pragma unroll
  for (int mi = 0; mi < 4; ++mi)
#pragma unroll
    for (int ni = 0; ni < 4; ++ni)
#pragma unroll
      for (int r = 0; r < 4; ++r) {
        const size_t t = tw + mi * 16 + lk * 4 + r;
        const int e = ni * 16 + lr;
        att[t * 512 + h * 64 + e] = f2bf(fmaxf(oacc[mi][ni][r], 0.0f));
      }
}

// ---------------- K3: out = LN(att @ Wo^T + bo)*g + b  (fused epilogue) -----
__global__ __launch_bounds__(512, 2) void gemm_ln(const ushort_t* __restrict__ A,
                                                  const ushort_t* __restrict__ Bm,
                                                  float* __restrict__ out,
                                                  const float* __restrict__ bo,
                                                  const float* __restrict__ lng,
                                                  const float* __restrict__ lnb) {
  __shared__ __align__(16) ushort_t As[2][128 * 32];   // 2 x 8 KB
  __shared__ __align__(16) ushort_t Bs[2][512 * 32];   // 2 x 32 KB
  __shared__ float red_s[4][128][2];
  __shared__ float tot_s[128][2];
  const int tid = threadIdx.x, wid = tid >> 6, lane = tid & 63;
  const int wr = wid >> 2, wc = wid & 3;
  const int lr = lane & 15, lk = lane >> 4;
  const int row0 = blockIdx.x * 128;
  float4v acc[4][8] = {};

  const int la = lane * 16;
  const int ar = wid * 16 + (lane >> 2);
  const int acb = (lane & 3) * 16;

  auto stage = [&](int buf, int s) {
    const int k0b = s * 64;
    gload16((const char*)A + (size_t)(row0 + ar) * 1024 + k0b + acb,
            (char*)&As[buf][0] + wid * 1024);
#pragma unroll
    for (int i = 0; i < 4; ++i) {
      const int dst = (wid * 4 + i) * 1024;
      const int br = (dst + la) >> 6;
      const int bcb = la & 63;
      gload16((const char*)Bm + (size_t)br * 1024 + k0b + bcb,
              (char*)&Bs[buf][0] + dst);
    }
  };

  stage(0, 0);
  __syncthreads();
  for (int s = 0; s < 16; ++s) {
    const int buf = s & 1;
    if (s < 15) stage(buf ^ 1, s + 1);
    short8 af[4], bf[8];
#pragma unroll
    for (int mi = 0; mi < 4; ++mi)
      af[mi] = *(const short8*)((const char*)&As[buf][0] + (wr * 64 + mi * 16 + lr) * 64 + lk * 16);
#pragma unroll
    for (int ni = 0; ni < 8; ++ni)
      bf[ni] = *(const short8*)((const char*)&Bs[buf][0] + (wc * 128 + ni * 16 + lr) * 64 + lk * 16);
#pragma unroll
    for (int mi = 0; mi < 4; ++mi)
#pragma unroll
      for (int ni = 0; ni < 8; ++ni)
        acc[mi][ni] = __builtin_amdgcn_mfma_f32_16x16x32_bf16(af[mi], bf[ni], acc[mi][ni], 0, 0, 0);
    __syncthreads();
  }

  float bov[8], gv[8], bv[8];
#pragma unroll
  for (int ni = 0; ni < 8; ++ni) {
    const int c = wc * 128 + ni * 16 + lr;
    bov[ni] = bo[c]; gv[ni] = lng[c]; bv[ni] = lnb[c];
  }
#pragma unroll
  for (int mi = 0; mi < 4; ++mi)
#pragma unroll
    for (int ni = 0; ni < 8; ++ni)
#pragma unroll
      for (int r = 0; r < 4; ++r)
        acc[mi][ni][r] += bov[ni];
#pragma unroll
  for (int mi = 0; mi < 4; ++mi)
#pragma unroll
    for (int r = 0; r < 4; ++r) {
      float s = 0.f, q = 0.f;
#pragma unroll
      for (int ni = 0; ni < 8; ++ni) { const float v = acc[mi][ni][r]; s += v; q += v * v; }
      s += __shfl_xor(s, 1); q += __shfl_xor(q, 1);
      s += __shfl_xor(s, 2); q += __shfl_xor(q, 2);
      s += __shfl_xor(s, 4); q += __shfl_xor(q, 4);
      s += __shfl_xor(s, 8); q += __shfl_xor(q, 8);
      if (lr == 0) {
        const int rb = wr * 64 + mi * 16 + lk * 4 + r;
        red_s[wc][rb][0] = s;
        red_s[wc][rb][1] = q;
      }
    }
  __syncthreads();
  if (tid < 128) {
    tot_s[tid][0] = red_s[0][tid][0] + red_s[1][tid][0] + red_s[2][tid][0] + red_s[3][tid][0];
    tot_s[tid][1] = red_s[0][tid][1] + red_s[1][tid][1] + red_s[2][tid][1] + red_s[3][tid][1];
  }
  __syncthreads();
#pragma unroll
  for (int mi = 0; mi < 4; ++mi)
#pragma unroll
    for (int r = 0; r < 4; ++r) {
      const int rb = wr * 64 + mi * 16 + lk * 4 + r;
      const float mu = tot_s[rb][0] * (1.f / 512.f);
      const float var = tot_s[rb][1] * (1.f / 512.f) - mu * mu;
      const float rs = rsqrtf(var + EPSF);
      float* op = out + (size_t)(row0 + rb) * 512 + wc * 128 + lr;
#pragma unroll
      for (int ni = 0; ni < 8; ++ni)
        op[ni * 16] = (acc[mi][ni][r] - mu) * rs * gv[ni] + bv[ni];
    }
}

extern "C" void kernel_launch(void* const* d_in, const int* in_sizes, int n_in,
                              void* d_out, int out_size, void* d_ws, size_t ws_size,
                              hipStream_t stream) {
  const float* X       = (const float*)d_in[0];
  // d_in[1] = batch_scopes (int64) — contiguous equal scopes, unused
  const float* Wq      = (const float*)d_in[2];
  const float* Wk      = (const float*)d_in[3];
  const float* Wv      = (const float*)d_in[4];
  const float* Wr      = (const float*)d_in[5];
  const float* w_alpha = (const float*)d_in[6];
  const float* w_beta  = (const float*)d_in[7];
  const float* Wo      = (const float*)d_in[8];
  const float* bo      = (const float*)d_in[9];
  const float* ln_g    = (const float*)d_in[10];
  const float* ln_b    = (const float*)d_in[11];

  char* ws = (char*)d_ws;
  ushort_t* Xb      = (ushort_t*)(ws);              // 67,108,864 B
  ushort_t* Wqkv    = (ushort_t*)(ws + 67108864);   //  1,572,864 B
  ushort_t* Wob     = (ushort_t*)(ws + 68681728);   //    524,288 B
  ushort_t* QKV     = (ushort_t*)(ws + 69206016);   // 201,326,592 B
  float*    gq_part = (float*)(ws + 270532608);     //    524,288 B
  float*    gk_part = (float*)(ws + 271056896);     //    524,288 B
  ushort_t* att     = Xb;                           // alias: Xb dead after K1
  float* out = (float*)d_out;

  hipLaunchKernelGGL(cvt_x, dim3(16384), dim3(256), 0, stream, X, Xb);
  hipLaunchKernelGGL(cvt_w, dim3(4096), dim3(256), 0, stream, Wq, Wk, Wv, Wo, Wqkv, Wob);
  hipLaunchKernelGGL(gemm_qkv, dim3(256), dim3(512), 0, stream, Xb, Wqkv, QKV);
  hipLaunchKernelGGL(reduce_gq, dim3(2048), dim3(256), 0, stream, QKV, w_alpha, gq_part);
  hipLaunchKernelGGL(reduce_gk, dim3(2048), dim3(256), 0, stream, QKV, w_beta, gq_part, gk_part);
  hipLaunchKernelGGL(att_k, dim3(2048), dim3(256), 0, stream, QKV, Wr, gk_part, att);
  hipLaunchKernelGGL(gemm_ln, dim3(512), dim3(512), 0, stream,
                     att, Wob, out, bo, ln_g, ln_b);
}

// Round 6
// 347.812 us; speedup vs baseline: 1.4524x; 1.4524x over previous
//
#include <hip/hip_runtime.h>
#include <stdint.h>

// BondFastAttention on MI355X (gfx950)
// B=64 graphs x L=1024 bonds, HID=512, HEADS=8, D=64. Contiguous equal scopes
// -> pad_sequence == reshape, so batch_scopes is ignored.
//
// Pipeline (round 6):
//   K0  cvt_all: X f32 -> bf16 (Xb); Wq|Wk|Wv -> Wqkv bf16; Wo -> bf16
//   K1  gemm8p:  QKV = Xb @ Wqkv^T -- round-4 proven 256^2 4-phase counted-
//                vmcnt kernel, UNCHANGED K-loop; epilogue additionally folds
//                the alpha/gq reduction for Q-blocks (tn<2): wave (wr,wc)
//                holds head tn*4+wc fully in acc -> softmax_D + token-sum
//                in-register, writes gq_part[bh][8][64].
//   R2  reduce_gk: gk partials (folds 8 gq sub-chunks in prologue)
//   R3  att_k:   att = relu([V|Q] @ [M|I]^T), M = Wr*gk (identity-MFMA Q-add)
//   K3  gemm_ln: out = LN(att @ Wo^T + bo)*g + b
//
// ws: Xb 0..67108864 | Wqkv ..68681728 | Wob ..69206016 | QKV ..270532608 |
//     gq_part ..271581184 (1 MB) | gk_part ..272105472 (512 KB)
// att aliases Xb (Xb dead after K1).

#define SCALE_F 0.125f   // D^-0.5
#define EPSF 1e-5f

typedef __attribute__((ext_vector_type(8))) short short8;
typedef __attribute__((ext_vector_type(4))) float float4v;
typedef unsigned short ushort_t;

__device__ __forceinline__ ushort_t f2bf(float f) {
  uint32_t u = __builtin_bit_cast(uint32_t, f);
  u += 0x7fffu + ((u >> 16) & 1u);          // round-to-nearest-even
  return (ushort_t)(u >> 16);
}
__device__ __forceinline__ float bf2f(ushort_t s) {
  uint32_t u = ((uint32_t)s) << 16;
  return __builtin_bit_cast(float, u);
}

// async global->LDS, 16B per lane; LDS dest = wave-uniform base + lane*16
__device__ __forceinline__ void gload16(const void* g, void* l) {
  __builtin_amdgcn_global_load_lds(
      (__attribute__((address_space(1))) char*)(char*)const_cast<void*>(g),
      (__attribute__((address_space(3))) char*)(char*)l, 16, 0, 0);
}

#define BARR() asm volatile("s_barrier" ::: "memory")
#define LGKM0() do { asm volatile("s_waitcnt lgkmcnt(0)" ::: "memory"); \
                     __builtin_amdgcn_sched_barrier(0); } while (0)

// ---------------- K0: fused conversions ----------------
// Segment 1: X (33,554,432 f32) -> Xb bf16, 8 elems/thread -> 4,194,304 thr.
// Segment 2: weights (1,048,576 f32) -> Wqkv/Wob, 1 elem/thread.
__global__ __launch_bounds__(256) void cvt_all(const float* __restrict__ X,
                                               const float* __restrict__ Wq,
                                               const float* __restrict__ Wk,
                                               const float* __restrict__ Wv,
                                               const float* __restrict__ Wo,
                                               ushort_t* __restrict__ Xb,
                                               ushort_t* __restrict__ Wqkv,
                                               ushort_t* __restrict__ Wob) {
  const int i = blockIdx.x * 256 + threadIdx.x;
  if (i < 4194304) {
    const float4v* src = (const float4v*)X;
    float4v v0 = src[(size_t)i * 2];
    float4v v1 = src[(size_t)i * 2 + 1];
    short8 o;
#pragma unroll
    for (int j = 0; j < 4; ++j) {
      o[j]     = (short)f2bf(v0[j]);
      o[j + 4] = (short)f2bf(v1[j]);
    }
    ((short8*)Xb)[i] = o;
  } else {
    const int j = i - 4194304;                 // 1,048,576 weight elems
    if (j < 262144)        Wqkv[j] = f2bf(Wq[j]);
    else if (j < 524288)   Wqkv[j] = f2bf(Wk[j - 262144]);
    else if (j < 786432)   Wqkv[j] = f2bf(Wv[j - 524288]);
    else                   Wob[j - 786432] = f2bf(Wo[j - 786432]);
  }
}

// ---------------- K1: QKV = Xb @ Wqkv^T, 256x256 tile, 8-phase schedule -----
// K-loop identical to round 3/4 (proven 140us). Epilogue adds the gq fold.
__global__ __launch_bounds__(512, 2) void gemm8p(const ushort_t* __restrict__ A,
                                                 const ushort_t* __restrict__ Bm,
                                                 ushort_t* __restrict__ C,
                                                 const float* __restrict__ w_alpha,
                                                 float* __restrict__ gq_part) {
  __shared__ __align__(16) char ldsA[65536];
  __shared__ __align__(16) char ldsB[65536];
  const int swz = (blockIdx.x & 7) * 192 + (blockIdx.x >> 3);
  const int tm = swz / 6, tn = swz % 6;
  const int row0 = tm * 256, col0 = tn * 256;
  const int tid = threadIdx.x, wid = tid >> 6, lane = tid & 63;
  const int wr = wid >> 2, wc = wid & 3;
  const int lr = lane & 15, lk = lane >> 4;
  const int xr = (lr & 7) << 4;               // read-side XOR (bytes)

  auto stageA = [&](int kt, int h) {
    const int slot = (2 * kt + h) & 3;
    const int rowbase = row0 + h * 128;
#pragma unroll
    for (int i = 0; i < 2; ++i) {
      const int o = i * 8192 + wid * 1024 + lane * 16;
      const int r = o >> 7, x = o & 127;
      gload16((const char*)A + (size_t)(rowbase + r) * 1024 + kt * 128 + (x ^ ((r & 7) << 4)),
              ldsA + slot * 16384 + i * 8192 + wid * 1024);
    }
  };
  auto stageB = [&](int kt, int h) {
    const int slot = (2 * kt + h) & 3;
    const int rowbase = col0 + h * 128;
#pragma unroll
    for (int i = 0; i < 2; ++i) {
      const int o = i * 8192 + wid * 1024 + lane * 16;
      const int r = o >> 7, x = o & 127;
      gload16((const char*)Bm + (size_t)(rowbase + r) * 1024 + kt * 128 + (x ^ ((r & 7) << 4)),
              ldsB + slot * 16384 + i * 8192 + wid * 1024);
    }
  };
  auto rdA = [&](int t, int mi, int kk) -> short8 {
    const int slot = (2 * t + wr) & 3;
    return *(const short8*)(ldsA + slot * 16384 + (mi * 16 + lr) * 128 +
                            ((kk * 64 + lk * 16) ^ xr));
  };
  auto rdB = [&](int t, int ni, int kk) -> short8 {
    const int slot = (2 * t + (wc >> 1)) & 3;
    return *(const short8*)(ldsB + slot * 16384 + ((wc & 1) * 64 + ni * 16 + lr) * 128 +
                            ((kk * 64 + lk * 16) ^ xr));
  };

  float4v acc[8][4] = {};

  stageA(0, 0); stageA(0, 1); stageB(0, 0); stageB(0, 1);
  stageA(1, 0); stageA(1, 1); stageB(1, 0);
  asm volatile("s_waitcnt vmcnt(6)" ::: "memory");
  BARR();

#pragma unroll
  for (int t = 0; t < 8; ++t) {
    short8 a0[4][2], a1[4][2], b0[2][2], b1[2][2];
#pragma unroll
    for (int mi = 0; mi < 4; ++mi)
#pragma unroll
      for (int kk = 0; kk < 2; ++kk) a0[mi][kk] = rdA(t, mi, kk);
#pragma unroll
    for (int ni = 0; ni < 2; ++ni)
#pragma unroll
      for (int kk = 0; kk < 2; ++kk) b0[ni][kk] = rdB(t, ni, kk);
    if (t + 1 < 8) stageB(t + 1, 1);
    BARR();
    LGKM0();
    __builtin_amdgcn_s_setprio(1);
#pragma unroll
    for (int kk = 0; kk < 2; ++kk)
#pragma unroll
      for (int mi = 0; mi < 4; ++mi)
#pragma unroll
        for (int ni = 0; ni < 2; ++ni)
          acc[mi][ni] = __builtin_amdgcn_mfma_f32_16x16x32_bf16(a0[mi][kk], b0[ni][kk], acc[mi][ni], 0, 0, 0);
    __builtin_amdgcn_s_setprio(0);
    __builtin_amdgcn_sched_barrier(0);
    BARR();
#pragma unroll
    for (int mi = 0; mi < 4; ++mi)
#pragma unroll
      for (int kk = 0; kk < 2; ++kk) a1[mi][kk] = rdA(t, mi + 4, kk);
#pragma unroll
    for (int ni = 0; ni < 2; ++ni)
#pragma unroll
      for (int kk = 0; kk < 2; ++kk) b1[ni][kk] = rdB(t, ni + 2, kk);
    BARR();
    LGKM0();
    __builtin_amdgcn_s_setprio(1);
#pragma unroll
    for (int kk = 0; kk < 2; ++kk)
#pragma unroll
      for (int mi = 0; mi < 4; ++mi)
#pragma unroll
        for (int ni = 0; ni < 2; ++ni)
          acc[mi][ni + 2] = __builtin_amdgcn_mfma_f32_16x16x32_bf16(a0[mi][kk], b1[ni][kk], acc[mi][ni + 2], 0, 0, 0);
    __builtin_amdgcn_s_setprio(0);
    __builtin_amdgcn_sched_barrier(0);
    BARR();
    if (t + 2 < 8) { stageA(t + 2, 0); stageA(t + 2, 1); }
    __builtin_amdgcn_sched_barrier(0);
    __builtin_amdgcn_s_setprio(1);
#pragma unroll
    for (int kk = 0; kk < 2; ++kk)
#pragma unroll
      for (int mi = 0; mi < 4; ++mi)
#pragma unroll
        for (int ni = 0; ni < 2; ++ni)
          acc[mi + 4][ni] = __builtin_amdgcn_mfma_f32_16x16x32_bf16(a1[mi][kk], b0[ni][kk], acc[mi + 4][ni], 0, 0, 0);
    __builtin_amdgcn_s_setprio(0);
    __builtin_amdgcn_sched_barrier(0);
    BARR();
    if (t + 2 < 8) stageB(t + 2, 0);
    __builtin_amdgcn_sched_barrier(0);
    __builtin_amdgcn_s_setprio(1);
#pragma unroll
    for (int kk = 0; kk < 2; ++kk)
#pragma unroll
      for (int mi = 0; mi < 4; ++mi)
#pragma unroll
        for (int ni = 0; ni < 2; ++ni)
          acc[mi + 4][ni + 2] = __builtin_amdgcn_mfma_f32_16x16x32_bf16(a1[mi][kk], b1[ni][kk], acc[mi + 4][ni + 2], 0, 0, 0);
    __builtin_amdgcn_s_setprio(0);
    __builtin_amdgcn_sched_barrier(0);
    if (t < 6) {
      asm volatile("s_waitcnt vmcnt(6)" ::: "memory");
    } else if (t == 6) {
      asm volatile("s_waitcnt vmcnt(0)" ::: "memory");
    }
    BARR();
  }

  // ---- C-write (unchanged): col=lane&15, row=(lane>>4)*4+r (m89) ----
#pragma unroll
  for (int mi = 0; mi < 8; ++mi)
#pragma unroll
    for (int ni = 0; ni < 4; ++ni) {
      const int col = col0 + wc * 64 + ni * 16 + lr;
#pragma unroll
      for (int r = 0; r < 4; ++r) {
        const int row = row0 + wr * 128 + mi * 16 + lk * 4 + r;
        C[(size_t)row * 1536 + col] = f2bf(acc[mi][ni][r]);
      }
    }

  // ---- gq fold: Q-blocks only (tn<2). Wave (wr,wc) holds head tn*4+wc
  // fully: row (mi,lk,r) has its 64 D-vals at (ni,lr). Softmax over D via
  // 4-reg + shfl_xor{1,2,4,8}; token-sum over this wave's 128 rows +
  // shfl_xor{16,32}; one writer per (bh, sub) -> deterministic. ----
  if (tn < 2) {
    float wa[4];
#pragma unroll
    for (int ni = 0; ni < 4; ++ni) wa[ni] = w_alpha[ni * 16 + lr] * SCALE_F;
    float gqa[4] = {0.f, 0.f, 0.f, 0.f};
#pragma unroll
    for (int mi = 0; mi < 8; ++mi)
#pragma unroll
      for (int r = 0; r < 4; ++r) {
        float sv[4];
#pragma unroll
        for (int ni = 0; ni < 4; ++ni) sv[ni] = acc[mi][ni][r] * wa[ni];
        float mx = fmaxf(fmaxf(sv[0], sv[1]), fmaxf(sv[2], sv[3]));
        mx = fmaxf(mx, __shfl_xor(mx, 1)); mx = fmaxf(mx, __shfl_xor(mx, 2));
        mx = fmaxf(mx, __shfl_xor(mx, 4)); mx = fmaxf(mx, __shfl_xor(mx, 8));
        float e[4], sm = 0.f;
#pragma unroll
        for (int ni = 0; ni < 4; ++ni) { e[ni] = __expf(sv[ni] - mx); sm += e[ni]; }
        sm += __shfl_xor(sm, 1); sm += __shfl_xor(sm, 2);
        sm += __shfl_xor(sm, 4); sm += __shfl_xor(sm, 8);
        const float inv = 1.0f / sm;
#pragma unroll
        for (int ni = 0; ni < 4; ++ni) gqa[ni] += e[ni] * inv * acc[mi][ni][r];
      }
#pragma unroll
    for (int ni = 0; ni < 4; ++ni) {
      gqa[ni] += __shfl_xor(gqa[ni], 16);
      gqa[ni] += __shfl_xor(gqa[ni], 32);
    }
    if (lk == 0) {
      const int bh = (tm >> 2) * 8 + tn * 4 + wc;      // b = tm/4, h = tn*4+wc
      const int sub = (tm & 3) * 2 + wr;               // 8 token sub-chunks
#pragma unroll
      for (int ni = 0; ni < 4; ++ni)
        gq_part[((size_t)bh * 8 + sub) * 64 + ni * 16 + lr] = gqa[ni];
    }
  }
}

// ---------------- R2: gk partials (folds 8 gq sub-chunks in prologue) -------
__global__ __launch_bounds__(256) void reduce_gk(const ushort_t* __restrict__ QKV,
                                                 const float* __restrict__ w_beta,
                                                 const float* __restrict__ gq_part,
                                                 float* __restrict__ gk_part) {
  const int bx = blockIdx.x, bh = bx >> 2, ch = bx & 3;
  const int b = bh >> 3, h = bh & 7;
  const int tid = threadIdx.x, wid = tid >> 6, lane = tid & 63;
  const int rsub = lane >> 3, dch = lane & 7;
  __shared__ float red[4][64];
  __shared__ float gq_s[64];
  if (tid < 64) {
    float s = 0.f;
#pragma unroll
    for (int c = 0; c < 8; ++c) s += gq_part[((size_t)bh * 8 + c) * 64 + tid];
    gq_s[tid] = s;
  }
  __syncthreads();
  float wb[8], gq[8];
#pragma unroll
  for (int j = 0; j < 8; ++j) {
    wb[j] = w_beta[dch * 8 + j] * SCALE_F;
    gq[j] = gq_s[dch * 8 + j];
  }
  const size_t base = (size_t)b * 1024 + ch * 256;
  float acc[8] = {0, 0, 0, 0, 0, 0, 0, 0};
  for (int it = 0; it < 8; ++it) {
    const size_t t = base + it * 32 + wid * 8 + rsub;
    short8 raw = *(const short8*)(QKV + t * 1536 + 512 + h * 64 + dch * 8);
    float p[8], s[8];
#pragma unroll
    for (int j = 0; j < 8; ++j) { p[j] = gq[j] * bf2f((ushort_t)raw[j]); s[j] = p[j] * wb[j]; }
    float m = s[0];
#pragma unroll
    for (int j = 1; j < 8; ++j) m = fmaxf(m, s[j]);
    m = fmaxf(m, __shfl_xor(m, 1)); m = fmaxf(m, __shfl_xor(m, 2)); m = fmaxf(m, __shfl_xor(m, 4));
    float e[8], sum = 0.f;
#pragma unroll
    for (int j = 0; j < 8; ++j) { e[j] = __expf(s[j] - m); sum += e[j]; }
    sum += __shfl_xor(sum, 1); sum += __shfl_xor(sum, 2); sum += __shfl_xor(sum, 4);
    const float inv = 1.0f / sum;
#pragma unroll
    for (int j = 0; j < 8; ++j) acc[j] += e[j] * inv * p[j];
  }
#pragma unroll
  for (int msk = 8; msk < 64; msk <<= 1)
#pragma unroll
    for (int j = 0; j < 8; ++j) acc[j] += __shfl_xor(acc[j], msk);
  if (lane < 8) {
#pragma unroll
    for (int j = 0; j < 8; ++j) red[wid][lane * 8 + j] = acc[j];
  }
  __syncthreads();
  if (tid < 64)
    gk_part[(size_t)bx * 64 + tid] = red[0][tid] + red[1][tid] + red[2][tid] + red[3][tid];
}

// ---------------- R3: att = relu([V|Q] @ [M|I]^T), M = Wr*gk ----------------
__global__ __launch_bounds__(256) void att_k(const ushort_t* __restrict__ QKV,
                                             const float* __restrict__ Wr,
                                             const float* __restrict__ gk_part,
                                             ushort_t* __restrict__ att) {
  const int bx = blockIdx.x, bh = bx >> 2, tc = bx & 3;
  const int b = bh >> 3, h = bh & 7;
  const int tid = threadIdx.x, wid = tid >> 6, lane = tid & 63;
  __shared__ float gk_s[64];
  __shared__ __align__(16) ushort_t Ml[64 * 72];
  if (tid < 64) {
    float s = 0.f;
#pragma unroll
    for (int c = 0; c < 4; ++c) s += gk_part[(size_t)(bh * 4 + c) * 64 + tid];
    gk_s[tid] = s;
  }
  __syncthreads();
  for (int i = tid; i < 4096; i += 256) {
    const int e = i >> 6, d = i & 63;
    Ml[e * 72 + d] = f2bf(Wr[i] * gk_s[d]);
  }
  __syncthreads();
  const int lr = lane & 15, lk = lane >> 4;
  short8 bfr[4][2], bfi[4][2];
#pragma unroll
  for (int ni = 0; ni < 4; ++ni)
#pragma unroll
    for (int ks = 0; ks < 2; ++ks) {
      bfr[ni][ks] = *(const short8*)&Ml[(ni * 16 + lr) * 72 + ks * 32 + lk * 8];
#pragma unroll
      for (int j = 0; j < 8; ++j)
        bfi[ni][ks][j] = (ni * 16 + lr == ks * 32 + lk * 8 + j) ? (short)0x3F80 : (short)0;
    }
  const size_t tw = (size_t)b * 1024 + tc * 256 + wid * 64;
  float4v oacc[4][4] = {};
#pragma unroll
  for (int ks = 0; ks < 2; ++ks) {
    short8 a[4], aq[4];
#pragma unroll
    for (int mi = 0; mi < 4; ++mi) {
      const size_t t = tw + mi * 16 + lr;
      a[mi]  = *(const short8*)(QKV + t * 1536 + 1024 + h * 64 + ks * 32 + lk * 8);  // V
      aq[mi] = *(const short8*)(QKV + t * 1536 +        h * 64 + ks * 32 + lk * 8);  // Q
    }
#pragma unroll
    for (int mi = 0; mi < 4; ++mi)
#pragma unroll
      for (int ni = 0; ni < 4; ++ni) {
        oacc[mi][ni] = __builtin_amdgcn_mfma_f32_16x16x32_bf16(a[mi],  bfr[ni][ks], oacc[mi][ni], 0, 0, 0);
        oacc[mi][ni] = __builtin_amdgcn_mfma_f32_16x16x32_bf16(aq[mi], bfi[ni][ks], oacc[mi][ni], 0, 0, 0);
      }
  }
#pragma unroll
  for (int mi = 0; mi < 4; ++mi)
#pragma unroll
    for (int ni = 0; ni < 4; ++ni)
#pragma unroll
      for (int r = 0; r < 4; ++r) {
        const size_t t = tw + mi * 16 + lk * 4 + r;
        const int e = ni * 16 + lr;
        att[t * 512 + h * 64 + e] = f2bf(fmaxf(oacc[mi][ni][r], 0.0f));
      }
}

// ---------------- K3: out = LN(att @ Wo^T + bo)*g + b  (fused epilogue) -----
__global__ __launch_bounds__(512, 2) void gemm_ln(const ushort_t* __restrict__ A,
                                                  const ushort_t* __restrict__ Bm,
                                                  float* __restrict__ out,
                                                  const float* __restrict__ bo,
                                                  const float* __restrict__ lng,
                                                  const float* __restrict__ lnb) {
  __shared__ __align__(16) ushort_t As[2][128 * 32];   // 2 x 8 KB
  __shared__ __align__(16) ushort_t Bs[2][512 * 32];   // 2 x 32 KB
  __shared__ float red_s[4][128][2];
  __shared__ float tot_s[128][2];
  const int tid = threadIdx.x, wid = tid >> 6, lane = tid & 63;
  const int wr = wid >> 2, wc = wid & 3;
  const int lr = lane & 15, lk = lane >> 4;
  const int row0 = blockIdx.x * 128;
  float4v acc[4][8] = {};

  const int la = lane * 16;
  const int ar = wid * 16 + (lane >> 2);
  const int acb = (lane & 3) * 16;

  auto stage = [&](int buf, int s) {
    const int k0b = s * 64;
    gload16((const char*)A + (size_t)(row0 + ar) * 1024 + k0b + acb,
            (char*)&As[buf][0] + wid * 1024);
#pragma unroll
    for (int i = 0; i < 4; ++i) {
      const int dst = (wid * 4 + i) * 1024;
      const int br = (dst + la) >> 6;
      const int bcb = la & 63;
      gload16((const char*)Bm + (size_t)br * 1024 + k0b + bcb,
              (char*)&Bs[buf][0] + dst);
    }
  };

  stage(0, 0);
  __syncthreads();
  for (int s = 0; s < 16; ++s) {
    const int buf = s & 1;
    if (s < 15) stage(buf ^ 1, s + 1);
    short8 af[4], bf[8];
#pragma unroll
    for (int mi = 0; mi < 4; ++mi)
      af[mi] = *(const short8*)((const char*)&As[buf][0] + (wr * 64 + mi * 16 + lr) * 64 + lk * 16);
#pragma unroll
    for (int ni = 0; ni < 8; ++ni)
      bf[ni] = *(const short8*)((const char*)&Bs[buf][0] + (wc * 128 + ni * 16 + lr) * 64 + lk * 16);
#pragma unroll
    for (int mi = 0; mi < 4; ++mi)
#pragma unroll
      for (int ni = 0; ni < 8; ++ni)
        acc[mi][ni] = __builtin_amdgcn_mfma_f32_16x16x32_bf16(af[mi], bf[ni], acc[mi][ni], 0, 0, 0);
    __syncthreads();
  }

  float bov[8], gv[8], bv[8];
#pragma unroll
  for (int ni = 0; ni < 8; ++ni) {
    const int c = wc * 128 + ni * 16 + lr;
    bov[ni] = bo[c]; gv[ni] = lng[c]; bv[ni] = lnb[c];
  }
#pragma unroll
  for (int mi = 0; mi < 4; ++mi)
#pragma unroll
    for (int ni = 0; ni < 8; ++ni)
#pragma unroll
      for (int r = 0; r < 4; ++r)
        acc[mi][ni][r] += bov[ni];
#pragma unroll
  for (int mi = 0; mi < 4; ++mi)
#pragma unroll
    for (int r = 0; r < 4; ++r) {
      float s = 0.f, q = 0.f;
#pragma unroll
      for (int ni = 0; ni < 8; ++ni) { const float v = acc[mi][ni][r]; s += v; q += v * v; }
      s += __shfl_xor(s, 1); q += __shfl_xor(q, 1);
      s += __shfl_xor(s, 2); q += __shfl_xor(q, 2);
      s += __shfl_xor(s, 4); q += __shfl_xor(q, 4);
      s += __shfl_xor(s, 8); q += __shfl_xor(q, 8);
      if (lr == 0) {
        const int rb = wr * 64 + mi * 16 + lk * 4 + r;
        red_s[wc][rb][0] = s;
        red_s[wc][rb][1] = q;
      }
    }
  __syncthreads();
  if (tid < 128) {
    tot_s[tid][0] = red_s[0][tid][0] + red_s[1][tid][0] + red_s[2][tid][0] + red_s[3][tid][0];
    tot_s[tid][1] = red_s[0][tid][1] + red_s[1][tid][1] + red_s[2][tid][1] + red_s[3][tid][1];
  }
  __syncthreads();
#pragma unroll
  for (int mi = 0; mi < 4; ++mi)
#pragma unroll
    for (int r = 0; r < 4; ++r) {
      const int rb = wr * 64 + mi * 16 + lk * 4 + r;
      const float mu = tot_s[rb][0] * (1.f / 512.f);
      const float var = tot_s[rb][1] * (1.f / 512.f) - mu * mu;
      const float rs = rsqrtf(var + EPSF);
      float* op = out + (size_t)(row0 + rb) * 512 + wc * 128 + lr;
#pragma unroll
      for (int ni = 0; ni < 8; ++ni)
        op[ni * 16] = (acc[mi][ni][r] - mu) * rs * gv[ni] + bv[ni];
    }
}

extern "C" void kernel_launch(void* const* d_in, const int* in_sizes, int n_in,
                              void* d_out, int out_size, void* d_ws, size_t ws_size,
                              hipStream_t stream) {
  const float* X       = (const float*)d_in[0];
  // d_in[1] = batch_scopes (int64) — contiguous equal scopes, unused
  const float* Wq      = (const float*)d_in[2];
  const float* Wk      = (const float*)d_in[3];
  const float* Wv      = (const float*)d_in[4];
  const float* Wr      = (const float*)d_in[5];
  const float* w_alpha = (const float*)d_in[6];
  const float* w_beta  = (const float*)d_in[7];
  const float* Wo      = (const float*)d_in[8];
  const float* bo      = (const float*)d_in[9];
  const float* ln_g    = (const float*)d_in[10];
  const float* ln_b    = (const float*)d_in[11];

  char* ws = (char*)d_ws;
  ushort_t* Xb      = (ushort_t*)(ws);              // 67,108,864 B
  ushort_t* Wqkv    = (ushort_t*)(ws + 67108864);   //  1,572,864 B
  ushort_t* Wob     = (ushort_t*)(ws + 68681728);   //    524,288 B
  ushort_t* QKV     = (ushort_t*)(ws + 69206016);   // 201,326,592 B
  float*    gq_part = (float*)(ws + 270532608);     //  1,048,576 B (512bh x 8 x 64)
  float*    gk_part = (float*)(ws + 271581184);     //    524,288 B
  ushort_t* att     = Xb;                           // alias: Xb dead after K1
  float* out = (float*)d_out;

  hipLaunchKernelGGL(cvt_all, dim3(20480), dim3(256), 0, stream,
                     X, Wq, Wk, Wv, Wo, Xb, Wqkv, Wob);
  hipLaunchKernelGGL(gemm8p, dim3(1536), dim3(512), 0, stream,
                     Xb, Wqkv, QKV, w_alpha, gq_part);
  hipLaunchKernelGGL(reduce_gk, dim3(2048), dim3(256), 0, stream,
                     QKV, w_beta, gq_part, gk_part);
  hipLaunchKernelGGL(att_k, dim3(2048), dim3(256), 0, stream, QKV, Wr, gk_part, att);
  hipLaunchKernelGGL(gemm_ln, dim3(512), dim3(512), 0, stream,
                     att, Wob, out, bo, ln_g, ln_b);
}

// Round 7
// 326.216 us; speedup vs baseline: 1.5486x; 1.0662x over previous
//
#include <hip/hip_runtime.h>
#include <stdint.h>

// BondFastAttention on MI355X (gfx950)
// B=64 graphs x L=1024 bonds, HID=512, HEADS=8, D=64. Contiguous equal scopes
// -> pad_sequence == reshape, so batch_scopes is ignored.
//
// Pipeline (round 7):
//   K0  cvt_all: X f32 -> bf16 (Xb); Wq|Wk|Wv -> Wqkv bf16; Wo -> bf16
//   K1  gemm8p:  QKV = Xb @ Wqkv^T -- round-4 grid (1536 one-tile blocks,
//                XCD swizzle, epilogue-only stores) + 3-barrier inner body
//                (2-slot ring, batched ds_reads, 32-MFMA clusters, vmcnt(8)).
//   R1  reduce_gq: gq partials per (b,h,Lchunk)      [round-4 verbatim]
//   R2  reduce_gk: gk partials (folds gq partials)   [round-4 verbatim]
//   R3  att_k:   att = relu([V|Q] @ [M|I]^T), M = Wr*gk (identity-MFMA Q-add)
//   K3  gemm_ln: out = LN(att @ Wo^T + bo)*g + b
//
// ws: Xb 0..67108864 | Wqkv ..68681728 | Wob ..69206016 | QKV ..270532608 |
//     gq_part ..271056896 | gk_part ..271581184
// att aliases Xb (Xb dead after K1).

#define SCALE_F 0.125f   // D^-0.5
#define EPSF 1e-5f

typedef __attribute__((ext_vector_type(8))) short short8;
typedef __attribute__((ext_vector_type(4))) float float4v;
typedef unsigned short ushort_t;

__device__ __forceinline__ ushort_t f2bf(float f) {
  uint32_t u = __builtin_bit_cast(uint32_t, f);
  u += 0x7fffu + ((u >> 16) & 1u);          // round-to-nearest-even
  return (ushort_t)(u >> 16);
}
__device__ __forceinline__ float bf2f(ushort_t s) {
  uint32_t u = ((uint32_t)s) << 16;
  return __builtin_bit_cast(float, u);
}

// async global->LDS, 16B per lane; LDS dest = wave-uniform base + lane*16
__device__ __forceinline__ void gload16(const void* g, void* l) {
  __builtin_amdgcn_global_load_lds(
      (__attribute__((address_space(1))) char*)(char*)const_cast<void*>(g),
      (__attribute__((address_space(3))) char*)(char*)l, 16, 0, 0);
}

#define SBAR() __builtin_amdgcn_s_barrier()
#define LGKM0() do { __builtin_amdgcn_sched_barrier(0);                 \
                     asm volatile("s_waitcnt lgkmcnt(0)" ::: "memory"); \
                     __builtin_amdgcn_sched_barrier(0); } while (0)

// ---------------- K0: fused conversions ----------------
__global__ __launch_bounds__(256) void cvt_all(const float* __restrict__ X,
                                               const float* __restrict__ Wq,
                                               const float* __restrict__ Wk,
                                               const float* __restrict__ Wv,
                                               const float* __restrict__ Wo,
                                               ushort_t* __restrict__ Xb,
                                               ushort_t* __restrict__ Wqkv,
                                               ushort_t* __restrict__ Wob) {
  const int i = blockIdx.x * 256 + threadIdx.x;
  if (i < 4194304) {
    const float4v* src = (const float4v*)X;
    float4v v0 = src[(size_t)i * 2];
    float4v v1 = src[(size_t)i * 2 + 1];
    short8 o;
#pragma unroll
    for (int j = 0; j < 4; ++j) {
      o[j]     = (short)f2bf(v0[j]);
      o[j + 4] = (short)f2bf(v1[j]);
    }
    ((short8*)Xb)[i] = o;
  } else {
    const int j = i - 4194304;                 // 1,048,576 weight elems
    if (j < 262144)        Wqkv[j] = f2bf(Wq[j]);
    else if (j < 524288)   Wqkv[j] = f2bf(Wk[j - 262144]);
    else if (j < 786432)   Wqkv[j] = f2bf(Wv[j - 524288]);
    else                   Wob[j - 786432] = f2bf(Wo[j - 786432]);
  }
}

// ---------------- K1: QKV = Xb @ Wqkv^T, 256x256 tile, 3-barrier body -------
// Grid 1536 (one tile per block), 512 thr = 8 waves (2 wr x 4 wc), wave tile
// 128x64. LDS: 2 slots x 32 KB per operand (full 256x64 K-tile per slot),
// XOR-swizzled (elem (r,c2) at byte r*128 + (c2 ^ ((r&7)<<4))); source
// pre-swizzled since global_load_lds writes linearly.
// Ledger: 8 loads/K-tile (4 A + 4 B per wave). Prologue stages K0,K1 ->
// vmcnt(8) = K0 landed. Per tile t: stage B(t+2) after BARR_a, A(t+2) after
// BARR_b; boundary vmcnt(8) (t<6) / vmcnt(0) (t==6) => K(t+1) landed.
// Overwrite safety: slot (t+2)&1 == t&1, but B-slot readers drain at LGKM0
// before BARR_a (stage issued after), A-slot readers at LGKM0 before BARR_b.
__global__ __launch_bounds__(512, 2) void gemm8p(const ushort_t* __restrict__ A,
                                                 const ushort_t* __restrict__ Bm,
                                                 ushort_t* __restrict__ C) {
  __shared__ __align__(16) char ldsA[65536];
  __shared__ __align__(16) char ldsB[65536];
  const int swz = (blockIdx.x & 7) * 192 + (blockIdx.x >> 3);
  const int tm = swz / 6, tn = swz % 6;
  const int row0 = tm * 256, col0 = tn * 256;
  const int tid = threadIdx.x, wid = tid >> 6, lane = tid & 63;
  const int wr = wid >> 2, wc = wid & 3;
  const int lr = lane & 15, lk = lane >> 4;
  const int xr = (lr & 7) << 4;               // read-side XOR (bytes)

  auto stageA = [&](int t) {                  // A K-tile t -> slot t&1
    const int kt = t;
#pragma unroll
    for (int i = 0; i < 4; ++i) {
      const int o = i * 8192 + wid * 1024 + lane * 16;
      const int r = o >> 7, x = o & 127;
      gload16((const char*)A + (size_t)(row0 + r) * 1024 + kt * 128 + (x ^ ((r & 7) << 4)),
              ldsA + (t & 1) * 32768 + i * 8192 + wid * 1024);
    }
  };
  auto stageB = [&](int t) {                  // B K-tile t -> slot t&1
    const int kt = t;
#pragma unroll
    for (int i = 0; i < 4; ++i) {
      const int o = i * 8192 + wid * 1024 + lane * 16;
      const int r = o >> 7, x = o & 127;
      gload16((const char*)Bm + (size_t)(col0 + r) * 1024 + kt * 128 + (x ^ ((r & 7) << 4)),
              ldsB + (t & 1) * 32768 + i * 8192 + wid * 1024);
    }
  };
  auto rdA = [&](int sl, int mi, int kk) -> short8 {
    return *(const short8*)(ldsA + sl * 32768 + (wr * 128 + mi * 16 + lr) * 128 +
                            ((kk * 64 + lk * 16) ^ xr));
  };
  auto rdB = [&](int sl, int ni, int kk) -> short8 {
    return *(const short8*)(ldsB + sl * 32768 + (wc * 64 + ni * 16 + lr) * 128 +
                            ((kk * 64 + lk * 16) ^ xr));
  };

  float4v acc[8][4] = {};

  // prologue: K0 (8 loads) then K1 (8); vmcnt(8) -> K0 landed
  stageA(0); stageB(0);
  stageA(1); stageB(1);
  asm volatile("s_waitcnt vmcnt(8)" ::: "memory");
  SBAR();

#pragma unroll
  for (int t = 0; t < 8; ++t) {
    const int sl = t & 1;
    short8 a0[4][2], a1[4][2], b[4][2];
    // ph1 reads: a0 (mi 0..3) + all b, from slot sl
#pragma unroll
    for (int mi = 0; mi < 4; ++mi)
#pragma unroll
      for (int kk = 0; kk < 2; ++kk) a0[mi][kk] = rdA(sl, mi, kk);
#pragma unroll
    for (int ni = 0; ni < 4; ++ni)
#pragma unroll
      for (int kk = 0; kk < 2; ++kk) b[ni][kk] = rdB(sl, ni, kk);
    LGKM0();                    // all B-slot + a0 reads in regs
    SBAR();                     // BARR_a: B slot sl free for re-stage
    if (t + 2 < 8) stageB(t + 2);
    // a1 reads issued early (overlap MFMA1); A slot re-staged only after BARR_b
#pragma unroll
    for (int mi = 0; mi < 4; ++mi)
#pragma unroll
      for (int kk = 0; kk < 2; ++kk) a1[mi][kk] = rdA(sl, mi + 4, kk);
    __builtin_amdgcn_s_setprio(1);
#pragma unroll
    for (int kk = 0; kk < 2; ++kk)
#pragma unroll
      for (int mi = 0; mi < 4; ++mi)
#pragma unroll
        for (int ni = 0; ni < 4; ++ni)
          acc[mi][ni] = __builtin_amdgcn_mfma_f32_16x16x32_bf16(a0[mi][kk], b[ni][kk], acc[mi][ni], 0, 0, 0);
    __builtin_amdgcn_s_setprio(0);
    LGKM0();                    // a1 reads done
    SBAR();                     // BARR_b: A slot sl free for re-stage
    if (t + 2 < 8) stageA(t + 2);
    __builtin_amdgcn_s_setprio(1);
#pragma unroll
    for (int kk = 0; kk < 2; ++kk)
#pragma unroll
      for (int mi = 0; mi < 4; ++mi)
#pragma unroll
        for (int ni = 0; ni < 4; ++ni)
          acc[mi + 4][ni] = __builtin_amdgcn_mfma_f32_16x16x32_bf16(a1[mi][kk], b[ni][kk], acc[mi + 4][ni], 0, 0, 0);
    __builtin_amdgcn_s_setprio(0);
    __builtin_amdgcn_sched_barrier(0);
    if (t < 6) {
      asm volatile("s_waitcnt vmcnt(8)" ::: "memory");   // K(t+1) landed
    } else if (t == 6) {
      asm volatile("s_waitcnt vmcnt(0)" ::: "memory");   // K7 landed
    }
    SBAR();                     // BARR_c
  }

  // epilogue: C/D col=lane&15, row=(lane>>4)*4+r (m89-verified)
#pragma unroll
  for (int mi = 0; mi < 8; ++mi)
#pragma unroll
    for (int ni = 0; ni < 4; ++ni) {
      const int col = col0 + wc * 64 + ni * 16 + lr;
#pragma unroll
      for (int r = 0; r < 4; ++r) {
        const int row = row0 + wr * 128 + mi * 16 + lk * 4 + r;
        C[(size_t)row * 1536 + col] = f2bf(acc[mi][ni][r]);
      }
    }
}

// ---------------- R1: gq partials ----------------
// Grid 2048 = (bh=512) x (ch=4); 256 thr. Each block: 256 tokens.
__global__ __launch_bounds__(256) void reduce_gq(const ushort_t* __restrict__ QKV,
                                                 const float* __restrict__ w_alpha,
                                                 float* __restrict__ gq_part) {
  const int bx = blockIdx.x, bh = bx >> 2, ch = bx & 3;
  const int b = bh >> 3, h = bh & 7;
  const int tid = threadIdx.x, wid = tid >> 6, lane = tid & 63;
  const int rsub = lane >> 3, dch = lane & 7;
  __shared__ float red[4][64];
  float wa[8];
#pragma unroll
  for (int j = 0; j < 8; ++j) wa[j] = w_alpha[dch * 8 + j] * SCALE_F;
  const size_t base = (size_t)b * 1024 + ch * 256;
  float acc[8] = {0, 0, 0, 0, 0, 0, 0, 0};
  for (int it = 0; it < 8; ++it) {
    const size_t t = base + it * 32 + wid * 8 + rsub;
    short8 raw = *(const short8*)(QKV + t * 1536 + h * 64 + dch * 8);
    float q[8], s[8];
#pragma unroll
    for (int j = 0; j < 8; ++j) { q[j] = bf2f((ushort_t)raw[j]); s[j] = q[j] * wa[j]; }
    float m = s[0];
#pragma unroll
    for (int j = 1; j < 8; ++j) m = fmaxf(m, s[j]);
    m = fmaxf(m, __shfl_xor(m, 1)); m = fmaxf(m, __shfl_xor(m, 2)); m = fmaxf(m, __shfl_xor(m, 4));
    float e[8], sum = 0.f;
#pragma unroll
    for (int j = 0; j < 8; ++j) { e[j] = __expf(s[j] - m); sum += e[j]; }
    sum += __shfl_xor(sum, 1); sum += __shfl_xor(sum, 2); sum += __shfl_xor(sum, 4);
    const float inv = 1.0f / sum;
#pragma unroll
    for (int j = 0; j < 8; ++j) acc[j] += e[j] * inv * q[j];
  }
#pragma unroll
  for (int msk = 8; msk < 64; msk <<= 1)
#pragma unroll
    for (int j = 0; j < 8; ++j) acc[j] += __shfl_xor(acc[j], msk);
  if (lane < 8) {
#pragma unroll
    for (int j = 0; j < 8; ++j) red[wid][lane * 8 + j] = acc[j];
  }
  __syncthreads();
  if (tid < 64)
    gq_part[(size_t)bx * 64 + tid] = red[0][tid] + red[1][tid] + red[2][tid] + red[3][tid];
}

// ---------------- R2: gk partials (folds gq partials in prologue) ----------
__global__ __launch_bounds__(256) void reduce_gk(const ushort_t* __restrict__ QKV,
                                                 const float* __restrict__ w_beta,
                                                 const float* __restrict__ gq_part,
                                                 float* __restrict__ gk_part) {
  const int bx = blockIdx.x, bh = bx >> 2, ch = bx & 3;
  const int b = bh >> 3, h = bh & 7;
  const int tid = threadIdx.x, wid = tid >> 6, lane = tid & 63;
  const int rsub = lane >> 3, dch = lane & 7;
  __shared__ float red[4][64];
  __shared__ float gq_s[64];
  if (tid < 64) {
    float s = 0.f;
#pragma unroll
    for (int c = 0; c < 4; ++c) s += gq_part[(size_t)(bh * 4 + c) * 64 + tid];
    gq_s[tid] = s;
  }
  __syncthreads();
  float wb[8], gq[8];
#pragma unroll
  for (int j = 0; j < 8; ++j) {
    wb[j] = w_beta[dch * 8 + j] * SCALE_F;
    gq[j] = gq_s[dch * 8 + j];
  }
  const size_t base = (size_t)b * 1024 + ch * 256;
  float acc[8] = {0, 0, 0, 0, 0, 0, 0, 0};
  for (int it = 0; it < 8; ++it) {
    const size_t t = base + it * 32 + wid * 8 + rsub;
    short8 raw = *(const short8*)(QKV + t * 1536 + 512 + h * 64 + dch * 8);
    float p[8], s[8];
#pragma unroll
    for (int j = 0; j < 8; ++j) { p[j] = gq[j] * bf2f((ushort_t)raw[j]); s[j] = p[j] * wb[j]; }
    float m = s[0];
#pragma unroll
    for (int j = 1; j < 8; ++j) m = fmaxf(m, s[j]);
    m = fmaxf(m, __shfl_xor(m, 1)); m = fmaxf(m, __shfl_xor(m, 2)); m = fmaxf(m, __shfl_xor(m, 4));
    float e[8], sum = 0.f;
#pragma unroll
    for (int j = 0; j < 8; ++j) { e[j] = __expf(s[j] - m); sum += e[j]; }
    sum += __shfl_xor(sum, 1); sum += __shfl_xor(sum, 2); sum += __shfl_xor(sum, 4);
    const float inv = 1.0f / sum;
#pragma unroll
    for (int j = 0; j < 8; ++j) acc[j] += e[j] * inv * p[j];
  }
#pragma unroll
  for (int msk = 8; msk < 64; msk <<= 1)
#pragma unroll
    for (int j = 0; j < 8; ++j) acc[j] += __shfl_xor(acc[j], msk);
  if (lane < 8) {
#pragma unroll
    for (int j = 0; j < 8; ++j) red[wid][lane * 8 + j] = acc[j];
  }
  __syncthreads();
  if (tid < 64)
    gk_part[(size_t)bx * 64 + tid] = red[0][tid] + red[1][tid] + red[2][tid] + red[3][tid];
}

// ---------------- R3: att = relu([V|Q] @ [M|I]^T), M = Wr*gk ----------------
__global__ __launch_bounds__(256) void att_k(const ushort_t* __restrict__ QKV,
                                             const float* __restrict__ Wr,
                                             const float* __restrict__ gk_part,
                                             ushort_t* __restrict__ att) {
  const int bx = blockIdx.x, bh = bx >> 2, tc = bx & 3;
  const int b = bh >> 3, h = bh & 7;
  const int tid = threadIdx.x, wid = tid >> 6, lane = tid & 63;
  __shared__ float gk_s[64];
  __shared__ __align__(16) ushort_t Ml[64 * 72];
  if (tid < 64) {
    float s = 0.f;
#pragma unroll
    for (int c = 0; c < 4; ++c) s += gk_part[(size_t)(bh * 4 + c) * 64 + tid];
    gk_s[tid] = s;
  }
  __syncthreads();
  for (int i = tid; i < 4096; i += 256) {
    const int e = i >> 6, d = i & 63;
    Ml[e * 72 + d] = f2bf(Wr[i] * gk_s[d]);
  }
  __syncthreads();
  const int lr = lane & 15, lk = lane >> 4;
  short8 bfr[4][2], bfi[4][2];
#pragma unroll
  for (int ni = 0; ni < 4; ++ni)
#pragma unroll
    for (int ks = 0; ks < 2; ++ks) {
      bfr[ni][ks] = *(const short8*)&Ml[(ni * 16 + lr) * 72 + ks * 32 + lk * 8];
#pragma unroll
      for (int j = 0; j < 8; ++j)
        bfi[ni][ks][j] = (ni * 16 + lr == ks * 32 + lk * 8 + j) ? (short)0x3F80 : (short)0;
    }
  const size_t tw = (size_t)b * 1024 + tc * 256 + wid * 64;
  float4v oacc[4][4] = {};
#pragma unroll
  for (int ks = 0; ks < 2; ++ks) {
    short8 a[4], aq[4];
#pragma unroll
    for (int mi = 0; mi < 4; ++mi) {
      const size_t t = tw + mi * 16 + lr;
      a[mi]  = *(const short8*)(QKV + t * 1536 + 1024 + h * 64 + ks * 32 + lk * 8);  // V
      aq[mi] = *(const short8*)(QKV + t * 1536 +        h * 64 + ks * 32 + lk * 8);  // Q
    }
#pragma unroll
    for (int mi = 0; mi < 4; ++mi)
#pragma unroll
      for (int ni = 0; ni < 4; ++ni) {
        oacc[mi][ni] = __builtin_amdgcn_mfma_f32_16x16x32_bf16(a[mi],  bfr[ni][ks], oacc[mi][ni], 0, 0, 0);
        oacc[mi][ni] = __builtin_amdgcn_mfma_f32_16x16x32_bf16(aq[mi], bfi[ni][ks], oacc[mi][ni], 0, 0, 0);
      }
  }
#pragma unroll
  for (int mi = 0; mi < 4; ++mi)
#pragma unroll
    for (int ni = 0; ni < 4; ++ni)
#pragma unroll
      for (int r = 0; r < 4; ++r) {
        const size_t t = tw + mi * 16 + lk * 4 + r;
        const int e = ni * 16 + lr;
        att[t * 512 + h * 64 + e] = f2bf(fmaxf(oacc[mi][ni][r], 0.0f));
      }
}

// ---------------- K3: out = LN(att @ Wo^T + bo)*g + b  (fused epilogue) -----
__global__ __launch_bounds__(512, 2) void gemm_ln(const ushort_t* __restrict__ A,
                                                  const ushort_t* __restrict__ Bm,
                                                  float* __restrict__ out,
                                                  const float* __restrict__ bo,
                                                  const float* __restrict__ lng,
                                                  const float* __restrict__ lnb) {
  __shared__ __align__(16) ushort_t As[2][128 * 32];   // 2 x 8 KB
  __shared__ __align__(16) ushort_t Bs[2][512 * 32];   // 2 x 32 KB
  __shared__ float red_s[4][128][2];
  __shared__ float tot_s[128][2];
  const int tid = threadIdx.x, wid = tid >> 6, lane = tid & 63;
  const int wr = wid >> 2, wc = wid & 3;
  const int lr = lane & 15, lk = lane >> 4;
  const int row0 = blockIdx.x * 128;
  float4v acc[4][8] = {};

  const int la = lane * 16;
  const int ar = wid * 16 + (lane >> 2);
  const int acb = (lane & 3) * 16;

  auto stage = [&](int buf, int s) {
    const int k0b = s * 64;
    gload16((const char*)A + (size_t)(row0 + ar) * 1024 + k0b + acb,
            (char*)&As[buf][0] + wid * 1024);
#pragma unroll
    for (int i = 0; i < 4; ++i) {
      const int dst = (wid * 4 + i) * 1024;
      const int br = (dst + la) >> 6;
      const int bcb = la & 63;
      gload16((const char*)Bm + (size_t)br * 1024 + k0b + bcb,
              (char*)&Bs[buf][0] + dst);
    }
  };

  stage(0, 0);
  __syncthreads();
  for (int s = 0; s < 16; ++s) {
    const int buf = s & 1;
    if (s < 15) stage(buf ^ 1, s + 1);
    short8 af[4], bf[8];
#pragma unroll
    for (int mi = 0; mi < 4; ++mi)
      af[mi] = *(const short8*)((const char*)&As[buf][0] + (wr * 64 + mi * 16 + lr) * 64 + lk * 16);
#pragma unroll
    for (int ni = 0; ni < 8; ++ni)
      bf[ni] = *(const short8*)((const char*)&Bs[buf][0] + (wc * 128 + ni * 16 + lr) * 64 + lk * 16);
#pragma unroll
    for (int mi = 0; mi < 4; ++mi)
#pragma unroll
      for (int ni = 0; ni < 8; ++ni)
        acc[mi][ni] = __builtin_amdgcn_mfma_f32_16x16x32_bf16(af[mi], bf[ni], acc[mi][ni], 0, 0, 0);
    __syncthreads();
  }

  float bov[8], gv[8], bv[8];
#pragma unroll
  for (int ni = 0; ni < 8; ++ni) {
    const int c = wc * 128 + ni * 16 + lr;
    bov[ni] = bo[c]; gv[ni] = lng[c]; bv[ni] = lnb[c];
  }
#pragma unroll
  for (int mi = 0; mi < 4; ++mi)
#pragma unroll
    for (int ni = 0; ni < 8; ++ni)
#pragma unroll
      for (int r = 0; r < 4; ++r)
        acc[mi][ni][r] += bov[ni];
#pragma unroll
  for (int mi = 0; mi < 4; ++mi)
#pragma unroll
    for (int r = 0; r < 4; ++r) {
      float s = 0.f, q = 0.f;
#pragma unroll
      for (int ni = 0; ni < 8; ++ni) { const float v = acc[mi][ni][r]; s += v; q += v * v; }
      s += __shfl_xor(s, 1); q += __shfl_xor(q, 1);
      s += __shfl_xor(s, 2); q += __shfl_xor(q, 2);
      s += __shfl_xor(s, 4); q += __shfl_xor(q, 4);
      s += __shfl_xor(s, 8); q += __shfl_xor(q, 8);
      if (lr == 0) {
        const int rb = wr * 64 + mi * 16 + lk * 4 + r;
        red_s[wc][rb][0] = s;
        red_s[wc][rb][1] = q;
      }
    }
  __syncthreads();
  if (tid < 128) {
    tot_s[tid][0] = red_s[0][tid][0] + red_s[1][tid][0] + red_s[2][tid][0] + red_s[3][tid][0];
    tot_s[tid][1] = red_s[0][tid][1] + red_s[1][tid][1] + red_s[2][tid][1] + red_s[3][tid][1];
  }
  __syncthreads();
#pragma unroll
  for (int mi = 0; mi < 4; ++mi)
#pragma unroll
    for (int r = 0; r < 4; ++r) {
      const int rb = wr * 64 + mi * 16 + lk * 4 + r;
      const float mu = tot_s[rb][0] * (1.f / 512.f);
      const float var = tot_s[rb][1] * (1.f / 512.f) - mu * mu;
      const float rs = rsqrtf(var + EPSF);
      float* op = out + (size_t)(row0 + rb) * 512 + wc * 128 + lr;
#pragma unroll
      for (int ni = 0; ni < 8; ++ni)
        op[ni * 16] = (acc[mi][ni][r] - mu) * rs * gv[ni] + bv[ni];
    }
}

extern "C" void kernel_launch(void* const* d_in, const int* in_sizes, int n_in,
                              void* d_out, int out_size, void* d_ws, size_t ws_size,
                              hipStream_t stream) {
  const float* X       = (const float*)d_in[0];
  // d_in[1] = batch_scopes (int64) — contiguous equal scopes, unused
  const float* Wq      = (const float*)d_in[2];
  const float* Wk      = (const float*)d_in[3];
  const float* Wv      = (const float*)d_in[4];
  const float* Wr      = (const float*)d_in[5];
  const float* w_alpha = (const float*)d_in[6];
  const float* w_beta  = (const float*)d_in[7];
  const float* Wo      = (const float*)d_in[8];
  const float* bo      = (const float*)d_in[9];
  const float* ln_g    = (const float*)d_in[10];
  const float* ln_b    = (const float*)d_in[11];

  char* ws = (char*)d_ws;
  ushort_t* Xb      = (ushort_t*)(ws);              // 67,108,864 B
  ushort_t* Wqkv    = (ushort_t*)(ws + 67108864);   //  1,572,864 B
  ushort_t* Wob     = (ushort_t*)(ws + 68681728);   //    524,288 B
  ushort_t* QKV     = (ushort_t*)(ws + 69206016);   // 201,326,592 B
  float*    gq_part = (float*)(ws + 270532608);     //    524,288 B
  float*    gk_part = (float*)(ws + 271056896);     //    524,288 B
  ushort_t* att     = Xb;                           // alias: Xb dead after K1
  float* out = (float*)d_out;

  hipLaunchKernelGGL(cvt_all, dim3(20480), dim3(256), 0, stream,
                     X, Wq, Wk, Wv, Wo, Xb, Wqkv, Wob);
  hipLaunchKernelGGL(gemm8p, dim3(1536), dim3(512), 0, stream, Xb, Wqkv, QKV);
  hipLaunchKernelGGL(reduce_gq, dim3(2048), dim3(256), 0, stream, QKV, w_alpha, gq_part);
  hipLaunchKernelGGL(reduce_gk, dim3(2048), dim3(256), 0, stream,
                     QKV, w_beta, gq_part, gk_part);
  hipLaunchKernelGGL(att_k, dim3(2048), dim3(256), 0, stream, QKV, Wr, gk_part, att);
  hipLaunchKernelGGL(gemm_ln, dim3(512), dim3(512), 0, stream,
                     att, Wob, out, bo, ln_g, ln_b);
}

// Round 8
// 322.419 us; speedup vs baseline: 1.5668x; 1.0118x over previous
//
#include <hip/hip_runtime.h>
#include <stdint.h>

// BondFastAttention on MI355X (gfx950)
// B=64 graphs x L=1024 bonds, HID=512, HEADS=8, D=64. Contiguous equal scopes
// -> pad_sequence == reshape, so batch_scopes is ignored.
//
// Pipeline (round 8):
//   K0  cvt_all: X f32 -> bf16 (Xb); Wq|Wk|Wv -> Wqkv bf16; Wo -> bf16
//   K1  gemm8p:  QKV = Xb @ Wqkv^T  [round-7 3-barrier body, unchanged]
//   R1  reduce_gq: gq partials per (b,h,Lchunk)      [unchanged]
//   R2  reduce_gk: gk partials (folds gq partials)   [unchanged]
//   K2  att_out: FUSED att + out-proj + LN. Per block (128 tokens):
//                per head: att16 = relu(V@(Wr*gk)^T + Q) via MFMA with
//                in-register M-frags + identity-MFMA Q-add -> bf16 LDS
//                att_full[128][520]; then out = att_full @ Wo^T + bo with
//                B-frags direct from global (L2-hot), LN epilogue in-register.
//
// ws: Xb 0..67108864 | Wqkv ..68681728 | Wob ..69206016 | QKV ..270532608 |
//     gq_part ..271056896 | gk_part ..271581184

#define SCALE_F 0.125f   // D^-0.5
#define EPSF 1e-5f

typedef __attribute__((ext_vector_type(8))) short short8;
typedef __attribute__((ext_vector_type(4))) float float4v;
typedef unsigned short ushort_t;

__device__ __forceinline__ ushort_t f2bf(float f) {
  uint32_t u = __builtin_bit_cast(uint32_t, f);
  u += 0x7fffu + ((u >> 16) & 1u);          // round-to-nearest-even
  return (ushort_t)(u >> 16);
}
__device__ __forceinline__ float bf2f(ushort_t s) {
  uint32_t u = ((uint32_t)s) << 16;
  return __builtin_bit_cast(float, u);
}

// async global->LDS, 16B per lane; LDS dest = wave-uniform base + lane*16
__device__ __forceinline__ void gload16(const void* g, void* l) {
  __builtin_amdgcn_global_load_lds(
      (__attribute__((address_space(1))) char*)(char*)const_cast<void*>(g),
      (__attribute__((address_space(3))) char*)(char*)l, 16, 0, 0);
}

#define SBAR() __builtin_amdgcn_s_barrier()
#define LGKM0() do { __builtin_amdgcn_sched_barrier(0);                 \
                     asm volatile("s_waitcnt lgkmcnt(0)" ::: "memory"); \
                     __builtin_amdgcn_sched_barrier(0); } while (0)

// ---------------- K0: fused conversions ----------------
__global__ __launch_bounds__(256) void cvt_all(const float* __restrict__ X,
                                               const float* __restrict__ Wq,
                                               const float* __restrict__ Wk,
                                               const float* __restrict__ Wv,
                                               const float* __restrict__ Wo,
                                               ushort_t* __restrict__ Xb,
                                               ushort_t* __restrict__ Wqkv,
                                               ushort_t* __restrict__ Wob) {
  const int i = blockIdx.x * 256 + threadIdx.x;
  if (i < 4194304) {
    const float4v* src = (const float4v*)X;
    float4v v0 = src[(size_t)i * 2];
    float4v v1 = src[(size_t)i * 2 + 1];
    short8 o;
#pragma unroll
    for (int j = 0; j < 4; ++j) {
      o[j]     = (short)f2bf(v0[j]);
      o[j + 4] = (short)f2bf(v1[j]);
    }
    ((short8*)Xb)[i] = o;
  } else {
    const int j = i - 4194304;                 // 1,048,576 weight elems
    if (j < 262144)        Wqkv[j] = f2bf(Wq[j]);
    else if (j < 524288)   Wqkv[j] = f2bf(Wk[j - 262144]);
    else if (j < 786432)   Wqkv[j] = f2bf(Wv[j - 524288]);
    else                   Wob[j - 786432] = f2bf(Wo[j - 786432]);
  }
}

// ---------------- K1: QKV = Xb @ Wqkv^T, 256x256 tile, 3-barrier body -------
// (round-7 proven: 130us, MfmaUtil 34%, 0 bank conflicts)
__global__ __launch_bounds__(512, 2) void gemm8p(const ushort_t* __restrict__ A,
                                                 const ushort_t* __restrict__ Bm,
                                                 ushort_t* __restrict__ C) {
  __shared__ __align__(16) char ldsA[65536];
  __shared__ __align__(16) char ldsB[65536];
  const int swz = (blockIdx.x & 7) * 192 + (blockIdx.x >> 3);
  const int tm = swz / 6, tn = swz % 6;
  const int row0 = tm * 256, col0 = tn * 256;
  const int tid = threadIdx.x, wid = tid >> 6, lane = tid & 63;
  const int wr = wid >> 2, wc = wid & 3;
  const int lr = lane & 15, lk = lane >> 4;
  const int xr = (lr & 7) << 4;               // read-side XOR (bytes)

  auto stageA = [&](int t) {                  // A K-tile t -> slot t&1
    const int kt = t;
#pragma unroll
    for (int i = 0; i < 4; ++i) {
      const int o = i * 8192 + wid * 1024 + lane * 16;
      const int r = o >> 7, x = o & 127;
      gload16((const char*)A + (size_t)(row0 + r) * 1024 + kt * 128 + (x ^ ((r & 7) << 4)),
              ldsA + (t & 1) * 32768 + i * 8192 + wid * 1024);
    }
  };
  auto stageB = [&](int t) {                  // B K-tile t -> slot t&1
    const int kt = t;
#pragma unroll
    for (int i = 0; i < 4; ++i) {
      const int o = i * 8192 + wid * 1024 + lane * 16;
      const int r = o >> 7, x = o & 127;
      gload16((const char*)Bm + (size_t)(col0 + r) * 1024 + kt * 128 + (x ^ ((r & 7) << 4)),
              ldsB + (t & 1) * 32768 + i * 8192 + wid * 1024);
    }
  };
  auto rdA = [&](int sl, int mi, int kk) -> short8 {
    return *(const short8*)(ldsA + sl * 32768 + (wr * 128 + mi * 16 + lr) * 128 +
                            ((kk * 64 + lk * 16) ^ xr));
  };
  auto rdB = [&](int sl, int ni, int kk) -> short8 {
    return *(const short8*)(ldsB + sl * 32768 + (wc * 64 + ni * 16 + lr) * 128 +
                            ((kk * 64 + lk * 16) ^ xr));
  };

  float4v acc[8][4] = {};

  stageA(0); stageB(0);
  stageA(1); stageB(1);
  asm volatile("s_waitcnt vmcnt(8)" ::: "memory");
  SBAR();

#pragma unroll
  for (int t = 0; t < 8; ++t) {
    const int sl = t & 1;
    short8 a0[4][2], a1[4][2], b[4][2];
#pragma unroll
    for (int mi = 0; mi < 4; ++mi)
#pragma unroll
      for (int kk = 0; kk < 2; ++kk) a0[mi][kk] = rdA(sl, mi, kk);
#pragma unroll
    for (int ni = 0; ni < 4; ++ni)
#pragma unroll
      for (int kk = 0; kk < 2; ++kk) b[ni][kk] = rdB(sl, ni, kk);
    LGKM0();
    SBAR();                     // BARR_a: B slot sl free for re-stage
    if (t + 2 < 8) stageB(t + 2);
#pragma unroll
    for (int mi = 0; mi < 4; ++mi)
#pragma unroll
      for (int kk = 0; kk < 2; ++kk) a1[mi][kk] = rdA(sl, mi + 4, kk);
    __builtin_amdgcn_s_setprio(1);
#pragma unroll
    for (int kk = 0; kk < 2; ++kk)
#pragma unroll
      for (int mi = 0; mi < 4; ++mi)
#pragma unroll
        for (int ni = 0; ni < 4; ++ni)
          acc[mi][ni] = __builtin_amdgcn_mfma_f32_16x16x32_bf16(a0[mi][kk], b[ni][kk], acc[mi][ni], 0, 0, 0);
    __builtin_amdgcn_s_setprio(0);
    LGKM0();
    SBAR();                     // BARR_b: A slot sl free for re-stage
    if (t + 2 < 8) stageA(t + 2);
    __builtin_amdgcn_s_setprio(1);
#pragma unroll
    for (int kk = 0; kk < 2; ++kk)
#pragma unroll
      for (int mi = 0; mi < 4; ++mi)
#pragma unroll
        for (int ni = 0; ni < 4; ++ni)
          acc[mi + 4][ni] = __builtin_amdgcn_mfma_f32_16x16x32_bf16(a1[mi][kk], b[ni][kk], acc[mi + 4][ni], 0, 0, 0);
    __builtin_amdgcn_s_setprio(0);
    __builtin_amdgcn_sched_barrier(0);
    if (t < 6) {
      asm volatile("s_waitcnt vmcnt(8)" ::: "memory");
    } else if (t == 6) {
      asm volatile("s_waitcnt vmcnt(0)" ::: "memory");
    }
    SBAR();                     // BARR_c
  }

#pragma unroll
  for (int mi = 0; mi < 8; ++mi)
#pragma unroll
    for (int ni = 0; ni < 4; ++ni) {
      const int col = col0 + wc * 64 + ni * 16 + lr;
#pragma unroll
      for (int r = 0; r < 4; ++r) {
        const int row = row0 + wr * 128 + mi * 16 + lk * 4 + r;
        C[(size_t)row * 1536 + col] = f2bf(acc[mi][ni][r]);
      }
    }
}

// ---------------- R1: gq partials ----------------
__global__ __launch_bounds__(256) void reduce_gq(const ushort_t* __restrict__ QKV,
                                                 const float* __restrict__ w_alpha,
                                                 float* __restrict__ gq_part) {
  const int bx = blockIdx.x, bh = bx >> 2, ch = bx & 3;
  const int b = bh >> 3, h = bh & 7;
  const int tid = threadIdx.x, wid = tid >> 6, lane = tid & 63;
  const int rsub = lane >> 3, dch = lane & 7;
  __shared__ float red[4][64];
  float wa[8];
#pragma unroll
  for (int j = 0; j < 8; ++j) wa[j] = w_alpha[dch * 8 + j] * SCALE_F;
  const size_t base = (size_t)b * 1024 + ch * 256;
  float acc[8] = {0, 0, 0, 0, 0, 0, 0, 0};
  for (int it = 0; it < 8; ++it) {
    const size_t t = base + it * 32 + wid * 8 + rsub;
    short8 raw = *(const short8*)(QKV + t * 1536 + h * 64 + dch * 8);
    float q[8], s[8];
#pragma unroll
    for (int j = 0; j < 8; ++j) { q[j] = bf2f((ushort_t)raw[j]); s[j] = q[j] * wa[j]; }
    float m = s[0];
#pragma unroll
    for (int j = 1; j < 8; ++j) m = fmaxf(m, s[j]);
    m = fmaxf(m, __shfl_xor(m, 1)); m = fmaxf(m, __shfl_xor(m, 2)); m = fmaxf(m, __shfl_xor(m, 4));
    float e[8], sum = 0.f;
#pragma unroll
    for (int j = 0; j < 8; ++j) { e[j] = __expf(s[j] - m); sum += e[j]; }
    sum += __shfl_xor(sum, 1); sum += __shfl_xor(sum, 2); sum += __shfl_xor(sum, 4);
    const float inv = 1.0f / sum;
#pragma unroll
    for (int j = 0; j < 8; ++j) acc[j] += e[j] * inv * q[j];
  }
#pragma unroll
  for (int msk = 8; msk < 64; msk <<= 1)
#pragma unroll
    for (int j = 0; j < 8; ++j) acc[j] += __shfl_xor(acc[j], msk);
  if (lane < 8) {
#pragma unroll
    for (int j = 0; j < 8; ++j) red[wid][lane * 8 + j] = acc[j];
  }
  __syncthreads();
  if (tid < 64)
    gq_part[(size_t)bx * 64 + tid] = red[0][tid] + red[1][tid] + red[2][tid] + red[3][tid];
}

// ---------------- R2: gk partials (folds gq partials in prologue) ----------
__global__ __launch_bounds__(256) void reduce_gk(const ushort_t* __restrict__ QKV,
                                                 const float* __restrict__ w_beta,
                                                 const float* __restrict__ gq_part,
                                                 float* __restrict__ gk_part) {
  const int bx = blockIdx.x, bh = bx >> 2, ch = bx & 3;
  const int b = bh >> 3, h = bh & 7;
  const int tid = threadIdx.x, wid = tid >> 6, lane = tid & 63;
  const int rsub = lane >> 3, dch = lane & 7;
  __shared__ float red[4][64];
  __shared__ float gq_s[64];
  if (tid < 64) {
    float s = 0.f;
#pragma unroll
    for (int c = 0; c < 4; ++c) s += gq_part[(size_t)(bh * 4 + c) * 64 + tid];
    gq_s[tid] = s;
  }
  __syncthreads();
  float wb[8], gq[8];
#pragma unroll
  for (int j = 0; j < 8; ++j) {
    wb[j] = w_beta[dch * 8 + j] * SCALE_F;
    gq[j] = gq_s[dch * 8 + j];
  }
  const size_t base = (size_t)b * 1024 + ch * 256;
  float acc[8] = {0, 0, 0, 0, 0, 0, 0, 0};
  for (int it = 0; it < 8; ++it) {
    const size_t t = base + it * 32 + wid * 8 + rsub;
    short8 raw = *(const short8*)(QKV + t * 1536 + 512 + h * 64 + dch * 8);
    float p[8], s[8];
#pragma unroll
    for (int j = 0; j < 8; ++j) { p[j] = gq[j] * bf2f((ushort_t)raw[j]); s[j] = p[j] * wb[j]; }
    float m = s[0];
#pragma unroll
    for (int j = 1; j < 8; ++j) m = fmaxf(m, s[j]);
    m = fmaxf(m, __shfl_xor(m, 1)); m = fmaxf(m, __shfl_xor(m, 2)); m = fmaxf(m, __shfl_xor(m, 4));
    float e[8], sum = 0.f;
#pragma unroll
    for (int j = 0; j < 8; ++j) { e[j] = __expf(s[j] - m); sum += e[j]; }
    sum += __shfl_xor(sum, 1); sum += __shfl_xor(sum, 2); sum += __shfl_xor(sum, 4);
    const float inv = 1.0f / sum;
#pragma unroll
    for (int j = 0; j < 8; ++j) acc[j] += e[j] * inv * p[j];
  }
#pragma unroll
  for (int msk = 8; msk < 64; msk <<= 1)
#pragma unroll
    for (int j = 0; j < 8; ++j) acc[j] += __shfl_xor(acc[j], msk);
  if (lane < 8) {
#pragma unroll
    for (int j = 0; j < 8; ++j) red[wid][lane * 8 + j] = acc[j];
  }
  __syncthreads();
  if (tid < 64)
    gk_part[(size_t)bx * 64 + tid] = red[0][tid] + red[1][tid] + red[2][tid] + red[3][tid];
}

// ---------------- K2: fused att + out-proj + LN ----------------
// Grid 512 (128 tokens each), 512 thr = 8 waves.
// Phase 1: per head h, wave w computes relu(V@(Wr*gk_h)^T + Q) for its 16
//   tokens (M-frags from Wr*gk in-register; Q via identity-MFMA, exact) and
//   stores bf16 into att_s[128][520] (pad 520 -> 2-way-free b128 reads).
// Phase 2: out = att_s @ Wob^T + bo, wave tile 64x128, A from LDS, B-frags
//   direct from global (Wob 512KB, L2-resident); LN epilogue in-register
//   (identical geometry to the previous gemm_ln kernel).
__global__ __launch_bounds__(512, 2) void att_out(const ushort_t* __restrict__ QKV,
                                                  const float* __restrict__ Wr,
                                                  const float* __restrict__ gk_part,
                                                  const ushort_t* __restrict__ Wob,
                                                  const float* __restrict__ bo,
                                                  const float* __restrict__ lng,
                                                  const float* __restrict__ lnb,
                                                  float* __restrict__ out) {
  __shared__ __align__(16) ushort_t att_s[128 * 520];   // 133,120 B
  __shared__ float gk_s[8][64];
  __shared__ float red_s[4][128][2];
  __shared__ float tot_s[128][2];
  const int bx = blockIdx.x;
  const int t0 = bx * 128;
  const int bg = bx >> 3;                    // graph index
  const int tid = threadIdx.x, wid = tid >> 6, lane = tid & 63;
  const int lr = lane & 15, lk = lane >> 4;

  // phase 0: fold gk partials for all 8 heads (one value per thread)
  {
    const int h = tid >> 6, d = tid & 63;
    const int bh = bg * 8 + h;
    float s = 0.f;
#pragma unroll
    for (int c = 0; c < 4; ++c) s += gk_part[(size_t)(bh * 4 + c) * 64 + d];
    gk_s[h][d] = s;
  }
  __syncthreads();

  // identity B-frags for the Q-add (exact 1.0 in bf16)
  short8 bfi[4][2];
#pragma unroll
  for (int ni = 0; ni < 4; ++ni)
#pragma unroll
    for (int ks = 0; ks < 2; ++ks)
#pragma unroll
      for (int j = 0; j < 8; ++j)
        bfi[ni][ks][j] = (ni * 16 + lr == ks * 32 + lk * 8 + j) ? (short)0x3F80 : (short)0;

  // ---- phase 1: per-head att into att_s ----
  const size_t trow = (size_t)t0 + wid * 16 + lr;   // this lane's token row
  for (int h = 0; h < 8; ++h) {
    short8 bfr[4][2];
#pragma unroll
    for (int ni = 0; ni < 4; ++ni)
#pragma unroll
      for (int ks = 0; ks < 2; ++ks) {
        const int e = ni * 16 + lr;
        const int k0 = ks * 32 + lk * 8;
        const float4v w0 = *(const float4v*)(Wr + e * 64 + k0);
        const float4v w1 = *(const float4v*)(Wr + e * 64 + k0 + 4);
        const float4v g0 = *(const float4v*)(&gk_s[h][k0]);
        const float4v g1 = *(const float4v*)(&gk_s[h][k0 + 4]);
        short8 rfrag;
#pragma unroll
        for (int j = 0; j < 4; ++j) {
          rfrag[j]     = (short)f2bf(w0[j] * g0[j]);
          rfrag[j + 4] = (short)f2bf(w1[j] * g1[j]);
        }
        bfr[ni][ks] = rfrag;
      }
    float4v pacc[4] = {};
#pragma unroll
    for (int ks = 0; ks < 2; ++ks) {
      const short8 av  = *(const short8*)(QKV + trow * 1536 + 1024 + h * 64 + ks * 32 + lk * 8);
      const short8 aqv = *(const short8*)(QKV + trow * 1536 +        h * 64 + ks * 32 + lk * 8);
#pragma unroll
      for (int ni = 0; ni < 4; ++ni) {
        pacc[ni] = __builtin_amdgcn_mfma_f32_16x16x32_bf16(av,  bfr[ni][ks], pacc[ni], 0, 0, 0);
        pacc[ni] = __builtin_amdgcn_mfma_f32_16x16x32_bf16(aqv, bfi[ni][ks], pacc[ni], 0, 0, 0);
      }
    }
#pragma unroll
    for (int ni = 0; ni < 4; ++ni)
#pragma unroll
      for (int r = 0; r < 4; ++r)
        att_s[(wid * 16 + lk * 4 + r) * 520 + h * 64 + ni * 16 + lr] =
            f2bf(fmaxf(pacc[ni][r], 0.0f));
  }
  __syncthreads();

  // ---- phase 2: out-GEMM (64x128 per wave) + LN ----
  const int wr = wid >> 2, wc = wid & 3;
  float4v acc[4][8] = {};
#pragma unroll 4
  for (int kc = 0; kc < 16; ++kc) {
    short8 a[4], bf[8];
#pragma unroll
    for (int mi = 0; mi < 4; ++mi)
      a[mi] = *(const short8*)(att_s + (wr * 64 + mi * 16 + lr) * 520 + kc * 32 + lk * 8);
#pragma unroll
    for (int ni = 0; ni < 8; ++ni)
      bf[ni] = *(const short8*)(Wob + (size_t)(wc * 128 + ni * 16 + lr) * 512 + kc * 32 + lk * 8);
#pragma unroll
    for (int mi = 0; mi < 4; ++mi)
#pragma unroll
      for (int ni = 0; ni < 8; ++ni)
        acc[mi][ni] = __builtin_amdgcn_mfma_f32_16x16x32_bf16(a[mi], bf[ni], acc[mi][ni], 0, 0, 0);
  }

  float bov[8], gv[8], bv[8];
#pragma unroll
  for (int ni = 0; ni < 8; ++ni) {
    const int c = wc * 128 + ni * 16 + lr;
    bov[ni] = bo[c]; gv[ni] = lng[c]; bv[ni] = lnb[c];
  }
#pragma unroll
  for (int mi = 0; mi < 4; ++mi)
#pragma unroll
    for (int ni = 0; ni < 8; ++ni)
#pragma unroll
      for (int r = 0; r < 4; ++r)
        acc[mi][ni][r] += bov[ni];
#pragma unroll
  for (int mi = 0; mi < 4; ++mi)
#pragma unroll
    for (int r = 0; r < 4; ++r) {
      float s = 0.f, q = 0.f;
#pragma unroll
      for (int ni = 0; ni < 8; ++ni) { const float v = acc[mi][ni][r]; s += v; q += v * v; }
      s += __shfl_xor(s, 1); q += __shfl_xor(q, 1);
      s += __shfl_xor(s, 2); q += __shfl_xor(q, 2);
      s += __shfl_xor(s, 4); q += __shfl_xor(q, 4);
      s += __shfl_xor(s, 8); q += __shfl_xor(q, 8);
      if (lr == 0) {
        const int rb = wr * 64 + mi * 16 + lk * 4 + r;
        red_s[wc][rb][0] = s;
        red_s[wc][rb][1] = q;
      }
    }
  __syncthreads();
  if (tid < 128) {
    tot_s[tid][0] = red_s[0][tid][0] + red_s[1][tid][0] + red_s[2][tid][0] + red_s[3][tid][0];
    tot_s[tid][1] = red_s[0][tid][1] + red_s[1][tid][1] + red_s[2][tid][1] + red_s[3][tid][1];
  }
  __syncthreads();
#pragma unroll
  for (int mi = 0; mi < 4; ++mi)
#pragma unroll
    for (int r = 0; r < 4; ++r) {
      const int rb = wr * 64 + mi * 16 + lk * 4 + r;
      const float mu = tot_s[rb][0] * (1.f / 512.f);
      const float var = tot_s[rb][1] * (1.f / 512.f) - mu * mu;
      const float rs = rsqrtf(var + EPSF);
      float* op = out + (size_t)(t0 + rb) * 512 + wc * 128 + lr;
#pragma unroll
      for (int ni = 0; ni < 8; ++ni)
        op[ni * 16] = (acc[mi][ni][r] - mu) * rs * gv[ni] + bv[ni];
    }
}

extern "C" void kernel_launch(void* const* d_in, const int* in_sizes, int n_in,
                              void* d_out, int out_size, void* d_ws, size_t ws_size,
                              hipStream_t stream) {
  const float* X       = (const float*)d_in[0];
  // d_in[1] = batch_scopes (int64) — contiguous equal scopes, unused
  const float* Wq      = (const float*)d_in[2];
  const float* Wk      = (const float*)d_in[3];
  const float* Wv      = (const float*)d_in[4];
  const float* Wr      = (const float*)d_in[5];
  const float* w_alpha = (const float*)d_in[6];
  const float* w_beta  = (const float*)d_in[7];
  const float* Wo      = (const float*)d_in[8];
  const float* bo      = (const float*)d_in[9];
  const float* ln_g    = (const float*)d_in[10];
  const float* ln_b    = (const float*)d_in[11];

  char* ws = (char*)d_ws;
  ushort_t* Xb      = (ushort_t*)(ws);              // 67,108,864 B
  ushort_t* Wqkv    = (ushort_t*)(ws + 67108864);   //  1,572,864 B
  ushort_t* Wob     = (ushort_t*)(ws + 68681728);   //    524,288 B
  ushort_t* QKV     = (ushort_t*)(ws + 69206016);   // 201,326,592 B
  float*    gq_part = (float*)(ws + 270532608);     //    524,288 B
  float*    gk_part = (float*)(ws + 271056896);     //    524,288 B
  float* out = (float*)d_out;

  hipLaunchKernelGGL(cvt_all, dim3(20480), dim3(256), 0, stream,
                     X, Wq, Wk, Wv, Wo, Xb, Wqkv, Wob);
  hipLaunchKernelGGL(gemm8p, dim3(1536), dim3(512), 0, stream, Xb, Wqkv, QKV);
  hipLaunchKernelGGL(reduce_gq, dim3(2048), dim3(256), 0, stream, QKV, w_alpha, gq_part);
  hipLaunchKernelGGL(reduce_gk, dim3(2048), dim3(256), 0, stream,
                     QKV, w_beta, gq_part, gk_part);
  hipLaunchKernelGGL(att_out, dim3(512), dim3(512), 0, stream,
                     QKV, Wr, gk_part, Wob, bo, ln_g, ln_b, out);
}